// Round 4
// baseline (3481.586 us; speedup 1.0000x reference)
//
#include <hip/hip_runtime.h>
#include <hip/hip_bf16.h>
#include <float.h>

#define N_   16
#define P_   4096
#define C_   128
#define HW_  784
#define G_   512
#define PTS  8
#define BLK  256

// ---------------------------------------------------------------------------
// Kernel 1: per-batch precompute of the glob contributions to gh and h1.
//   glob_gh[n][c] = sum_g enc_glob[n][g] * gw1[15+g][c]
//   glob_f1[n][c] = sum_g enc_glob[n][g] * fw1[15+g][c]
// ---------------------------------------------------------------------------
__global__ __launch_bounds__(256) void k_precompute(
    const float* __restrict__ enc_glob,   // 16x512
    const float* __restrict__ gw1,        // 527x128
    const float* __restrict__ fw1,        // 657x128
    float* __restrict__ glob_gh,          // 16x128
    float* __restrict__ glob_f1)          // 16x128
{
    const int n = blockIdx.x;
    const int c = threadIdx.x & 127;
    const int which = threadIdx.x >> 7;   // 0 -> gw1, 1 -> fw1
    const float* W = which ? fw1 : gw1;
    const float* g = enc_glob + n * G_;
    float acc = 0.f;
    for (int k = 0; k < G_; ++k)
        acc += g[k] * W[(15 + k) * C_ + c];
    (which ? glob_f1 : glob_gh)[n * C_ + c] = acc;
}

// ---------------------------------------------------------------------------
// Kernel 2: main per-point pipeline. 8 points per block, 256 threads.
// ---------------------------------------------------------------------------
__global__ __launch_bounds__(256) void k_main(
    const float* __restrict__ points,     // 16x4096x3
    const float* __restrict__ transform,  // 16x4096x12
    const float* __restrict__ filters,    // 16x128x784
    const float* __restrict__ sw1, const float* __restrict__ sb1,
    const float* __restrict__ sw2, const float* __restrict__ sb2,
    const float* __restrict__ gw1, const float* __restrict__ gb1,
    const float* __restrict__ gw2, const float* __restrict__ gb2,
    const float* __restrict__ fw1, const float* __restrict__ fb1,
    const float* __restrict__ fw2, const float* __restrict__ fb2,
    const float* __restrict__ fw3, const float* __restrict__ fb3,
    const float* __restrict__ glob_gh, const float* __restrict__ glob_f1,
    float* __restrict__ pre)              // 16x4096x3 (deform + points)
{
    __shared__ float s_x[PTS][16];        // [pt]: 0-2 points, 3-14 transform
    __shared__ float s_sh[PTS][C_];       // sh, later reused for h1
    __shared__ float s_gh[PTS][C_];       // gh, later reused for h2
    __shared__ float s_sf[PTS][C_];       // spat_map -> spat_feats
    __shared__ float s_attn[PTS][HW_];    // softmax attention
    __shared__ float s_chunk[C_][33];     // filters chunk (32 q, +1 pad)

    const int tid = threadIdx.x;
    const int blocks_per_n = P_ / PTS;    // 512
    const int n  = blockIdx.x / blocks_per_n;
    const int p0 = (blockIdx.x % blocks_per_n) * PTS;

    // ---- P1: load point + transform inputs -------------------------------
    if (tid < PTS * 16) {
        const int pt = tid >> 4, k = tid & 15;
        const int gp = n * P_ + p0 + pt;
        float v = 0.f;
        if (k < 3)       v = points[gp * 3 + k];
        else if (k < 15) v = transform[gp * 12 + (k - 3)];
        s_x[pt][k] = v;
    }
    __syncthreads();

    // ---- P2: sh = relu(spat_in @ sw1 + sb1) ------------------------------
    for (int idx = tid; idx < PTS * C_; idx += BLK) {
        const int pt = idx >> 7, c = idx & 127;
        float acc = sb1[c];
        #pragma unroll
        for (int k = 0; k < 15; ++k) acc += s_x[pt][k] * sw1[k * C_ + c];
        s_sh[pt][c] = fmaxf(acc, 0.f);
    }
    __syncthreads();

    // ---- P3: logits = sh @ sw2 + sb2, softmax over 784 (in registers) ----
    {
        const int pg = tid >> 5;          // point group 0..7
        const int l32 = tid & 31;
        float4 lg[7];
        #pragma unroll
        for (int j = 0; j < 7; ++j)
            lg[j] = make_float4(-FLT_MAX, -FLT_MAX, -FLT_MAX, -FLT_MAX);

        #pragma unroll
        for (int j = 0; j < 7; ++j) {
            const int q0 = j * 128 + l32 * 4;
            if (q0 < HW_) {
                float ax = 0.f, ay = 0.f, az = 0.f, aw = 0.f;
                for (int c = 0; c < C_; ++c) {
                    const float s = s_sh[pg][c];
                    const float4 w = *reinterpret_cast<const float4*>(sw2 + c * HW_ + q0);
                    ax += s * w.x; ay += s * w.y; az += s * w.z; aw += s * w.w;
                }
                lg[j].x = ax + sb2[q0 + 0];
                lg[j].y = ay + sb2[q0 + 1];
                lg[j].z = az + sb2[q0 + 2];
                lg[j].w = aw + sb2[q0 + 3];
            }
        }
        // max over the 784 logits of this point (32-thread group reduce)
        float mx = -FLT_MAX;
        #pragma unroll
        for (int j = 0; j < 7; ++j)
            mx = fmaxf(mx, fmaxf(fmaxf(lg[j].x, lg[j].y), fmaxf(lg[j].z, lg[j].w)));
        #pragma unroll
        for (int m = 16; m >= 1; m >>= 1) mx = fmaxf(mx, __shfl_xor(mx, m));
        // exp and sum
        float sum = 0.f;
        #pragma unroll
        for (int j = 0; j < 7; ++j) {
            const int q0 = j * 128 + l32 * 4;
            if (q0 < HW_) {
                lg[j].x = __expf(lg[j].x - mx);
                lg[j].y = __expf(lg[j].y - mx);
                lg[j].z = __expf(lg[j].z - mx);
                lg[j].w = __expf(lg[j].w - mx);
                sum += lg[j].x + lg[j].y + lg[j].z + lg[j].w;
            }
        }
        #pragma unroll
        for (int m = 16; m >= 1; m >>= 1) sum += __shfl_xor(sum, m);
        const float inv = 1.f / sum;
        #pragma unroll
        for (int j = 0; j < 7; ++j) {
            const int q0 = j * 128 + l32 * 4;
            if (q0 < HW_) {
                s_attn[pg][q0 + 0] = lg[j].x * inv;
                s_attn[pg][q0 + 1] = lg[j].y * inv;
                s_attn[pg][q0 + 2] = lg[j].z * inv;
                s_attn[pg][q0 + 3] = lg[j].w * inv;
            }
        }
    }
    __syncthreads();

    // ---- P4: spat_map[pt][c] = sum_q attn[pt][q] * filters[n][c][q] ------
    {
        float acc[4] = {0.f, 0.f, 0.f, 0.f};
        const size_t fbase = (size_t)n * C_ * HW_;
        for (int ch = 0; ch < 25; ++ch) {
            const int qb = ch * 32;
            const int qlen = (HW_ - qb) < 32 ? (HW_ - qb) : 32;
            for (int idx = tid; idx < C_ * 32; idx += BLK) {
                const int cc = idx >> 5, qq = idx & 31;
                if (qq < qlen) s_chunk[cc][qq] = filters[fbase + cc * HW_ + qb + qq];
            }
            __syncthreads();
            const int c = tid & 127, half = tid >> 7;
            #pragma unroll
            for (int pp = 0; pp < 4; ++pp) {
                const int pt = pp * 2 + half;
                float a = 0.f;
                for (int qq = 0; qq < qlen; ++qq)
                    a += s_attn[pt][qb + qq] * s_chunk[c][qq];
                acc[pp] += a;
            }
            __syncthreads();
        }
        const int c = tid & 127, half = tid >> 7;
        #pragma unroll
        for (int pp = 0; pp < 4; ++pp) s_sf[pp * 2 + half][c] = acc[pp];
    }
    __syncthreads();

    // ---- P5: gh = relu(gate_in @ gw1 + gb1) (glob part precomputed) ------
    for (int idx = tid; idx < PTS * C_; idx += BLK) {
        const int pt = idx >> 7, c = idx & 127;
        float acc = gb1[c] + glob_gh[n * C_ + c];
        #pragma unroll
        for (int k = 0; k < 15; ++k) acc += s_x[pt][k] * gw1[k * C_ + c];
        s_gh[pt][c] = fmaxf(acc, 0.f);
    }
    __syncthreads();

    // ---- P6: gattn = sigmoid(gh @ gw2 + gb2); spat_feats = gattn*spat_map -
    for (int idx = tid; idx < PTS * C_; idx += BLK) {
        const int pt = idx >> 7, c = idx & 127;
        float acc = gb2[c];
        for (int k = 0; k < C_; ++k) acc += s_gh[pt][k] * gw2[k * C_ + c];
        const float gat = 1.f / (1.f + __expf(-acc));
        s_sf[pt][c] *= gat;
    }
    __syncthreads();

    // ---- P7: h1 = relu(inputs @ fw1 + fb1) -------------------------------
    for (int idx = tid; idx < PTS * C_; idx += BLK) {
        const int pt = idx >> 7, c = idx & 127;
        float acc = fb1[c] + glob_f1[n * C_ + c];
        #pragma unroll
        for (int k = 0; k < 15; ++k) acc += s_x[pt][k] * fw1[k * C_ + c];
        const int p = p0 + pt;
        const float cx = -1.f + 2.f * (float)(p >> 6) / 63.f;
        const float cy = -1.f + 2.f * (float)(p & 63) / 63.f;
        acc += cx * fw1[527 * C_ + c] + cy * fw1[528 * C_ + c];
        for (int j = 0; j < C_; ++j) acc += s_sf[pt][j] * fw1[(529 + j) * C_ + c];
        s_sh[pt][c] = fmaxf(acc, 0.f);   // reuse s_sh for h1
    }
    __syncthreads();

    // ---- P8: h2 = relu(h1 @ fw2 + fb2) -----------------------------------
    for (int idx = tid; idx < PTS * C_; idx += BLK) {
        const int pt = idx >> 7, c = idx & 127;
        float acc = fb2[c];
        for (int k = 0; k < C_; ++k) acc += s_sh[pt][k] * fw2[k * C_ + c];
        s_gh[pt][c] = fmaxf(acc, 0.f);   // reuse s_gh for h2
    }
    __syncthreads();

    // ---- P9: deform = h2 @ fw3 + fb3; pre = deform + points --------------
    if (tid < PTS * 3) {
        const int pt = tid / 3, d = tid % 3;
        float acc = fb3[d];
        for (int k = 0; k < C_; ++k) acc += s_gh[pt][k] * fw3[k * 3 + d];
        pre[((size_t)(n * P_ + p0 + pt)) * 3 + d] = acc + s_x[pt][d];
    }
}

// ---------------------------------------------------------------------------
// Kernel 3: per-batch normalize in place: center by mean, divide by max norm.
// Output is f32 (the reference's output dtype). Safe in place: all cross-
// thread reads happen before the final loop, and in the final loop each
// thread reads exactly the locations it writes.
// ---------------------------------------------------------------------------
__global__ __launch_bounds__(256) void k_norm(float* __restrict__ out)
{
    __shared__ float red[12];
    const int n = blockIdx.x, tid = threadIdx.x;
    float* p = out + (size_t)n * P_ * 3;

    float sx = 0.f, sy = 0.f, sz = 0.f;
    for (int i = tid; i < P_; i += 256) {
        sx += p[i * 3 + 0]; sy += p[i * 3 + 1]; sz += p[i * 3 + 2];
    }
    #pragma unroll
    for (int m = 32; m >= 1; m >>= 1) {
        sx += __shfl_xor(sx, m); sy += __shfl_xor(sy, m); sz += __shfl_xor(sz, m);
    }
    const int wv = tid >> 6, ln = tid & 63;
    if (ln == 0) { red[wv * 3 + 0] = sx; red[wv * 3 + 1] = sy; red[wv * 3 + 2] = sz; }
    __syncthreads();
    const float meanx = (red[0] + red[3] + red[6] + red[9]) / (float)P_;
    const float meany = (red[1] + red[4] + red[7] + red[10]) / (float)P_;
    const float meanz = (red[2] + red[5] + red[8] + red[11]) / (float)P_;
    __syncthreads();

    float mm = 0.f;
    for (int i = tid; i < P_; i += 256) {
        const float dx = p[i * 3 + 0] - meanx;
        const float dy = p[i * 3 + 1] - meany;
        const float dz = p[i * 3 + 2] - meanz;
        mm = fmaxf(mm, dx * dx + dy * dy + dz * dz);
    }
    #pragma unroll
    for (int m = 32; m >= 1; m >>= 1) mm = fmaxf(mm, __shfl_xor(mm, m));
    if (ln == 0) red[wv] = mm;
    __syncthreads();
    mm = fmaxf(fmaxf(red[0], red[1]), fmaxf(red[2], red[3]));
    const float scale = 1.f / (sqrtf(mm) + 1e-8f);

    for (int i = tid; i < P_; i += 256) {
        p[i * 3 + 0] = (p[i * 3 + 0] - meanx) * scale;
        p[i * 3 + 1] = (p[i * 3 + 1] - meany) * scale;
        p[i * 3 + 2] = (p[i * 3 + 2] - meanz) * scale;
    }
}

// ---------------------------------------------------------------------------
extern "C" void kernel_launch(void* const* d_in, const int* in_sizes, int n_in,
                              void* d_out, int out_size, void* d_ws, size_t ws_size,
                              hipStream_t stream) {
    const float* points    = (const float*)d_in[0];
    const float* transform = (const float*)d_in[1];
    const float* filters   = (const float*)d_in[2];
    const float* enc_glob  = (const float*)d_in[3];
    const float* sw1 = (const float*)d_in[4];
    const float* sb1 = (const float*)d_in[5];
    const float* sw2 = (const float*)d_in[6];
    const float* sb2 = (const float*)d_in[7];
    const float* gw1 = (const float*)d_in[8];
    const float* gb1 = (const float*)d_in[9];
    const float* gw2 = (const float*)d_in[10];
    const float* gb2 = (const float*)d_in[11];
    const float* fw1 = (const float*)d_in[12];
    const float* fb1 = (const float*)d_in[13];
    const float* fw2 = (const float*)d_in[14];
    const float* fb2 = (const float*)d_in[15];
    const float* fw3 = (const float*)d_in[16];
    const float* fb3 = (const float*)d_in[17];

    float* ws = (float*)d_ws;
    float* glob_gh = ws;            // 16*128
    float* glob_f1 = ws + 2048;     // 16*128
    float* out = (float*)d_out;     // f32 output; also used as 'pre' staging

    k_precompute<<<N_, 256, 0, stream>>>(enc_glob, gw1, fw1, glob_gh, glob_f1);
    k_main<<<(N_ * P_) / PTS, 256, 0, stream>>>(
        points, transform, filters,
        sw1, sb1, sw2, sb2, gw1, gb1, gw2, gb2,
        fw1, fb1, fw2, fb2, fw3, fb3,
        glob_gh, glob_f1, out);
    k_norm<<<N_, 256, 0, stream>>>(out);
}

// Round 5
// 372.409 us; speedup vs baseline: 9.3488x; 9.3488x over previous
//
#include <hip/hip_runtime.h>
#include <hip/hip_bf16.h>
#include <float.h>

#define N_   16
#define P_   4096
#define C_   128
#define HW_  784
#define G_   512

typedef unsigned short u16;
typedef unsigned int   u32;
typedef __attribute__((ext_vector_type(8))) short bf16x8;   // 8 bf16 in 4 VGPRs
typedef __attribute__((ext_vector_type(4))) float f32x4;

#define MFMA(a,b,c) __builtin_amdgcn_mfma_f32_16x16x32_bf16((a),(b),(c),0,0,0)

// Cross-lane LDS visibility within a wave (no block barrier needed): drain
// LDS queue + pin scheduler (guide rule #18).
#define LDS_FENCE() do { asm volatile("s_waitcnt lgkmcnt(0)" ::: "memory"); \
                         __builtin_amdgcn_sched_barrier(0); } while (0)

__device__ __forceinline__ u16 f2b(float f) {
    __hip_bfloat16 h = __float2bfloat16(f);
    return *reinterpret_cast<u16*>(&h);
}
__device__ __forceinline__ float b2f(u16 u) {
    __hip_bfloat16 h = *reinterpret_cast<__hip_bfloat16*>(&u);
    return __bfloat162float(h);
}

// ---------------------------------------------------------------------------
// ws layout (bytes)
//   0       glob_gh  16x128 f32
//   8192    glob_f1  16x128 f32
//   16384   sw2t     784x128 bf16   sw2t[q][c]    = sw2[c][q]
//   217088  gw2t     128x128 bf16   gw2t[co][ci]  = gw2[ci][co]
//   249856  fw1bt    128x128 bf16   fw1bt[co][j]  = fw1[529+j][co]
//   282624  fw2t     128x128 bf16   fw2t[co][ci]  = fw2[ci][co]
//   315392  filt     16x128x800 bf16 (q padded 784->800 with zeros)
// ---------------------------------------------------------------------------
#define OFF_GLOB_GH 0
#define OFF_GLOB_F1 8192
#define OFF_SW2T    16384
#define OFF_GW2T    217088
#define OFF_FW1BT   249856
#define OFF_FW2T    282624
#define OFF_FILT    315392

// ---------------------------------------------------------------------------
__global__ __launch_bounds__(256) void k_prep_w(
    const float* __restrict__ sw2, const float* __restrict__ gw2,
    const float* __restrict__ fw1, const float* __restrict__ fw2,
    u16* __restrict__ sw2t, u16* __restrict__ gw2t,
    u16* __restrict__ fw1bt, u16* __restrict__ fw2t)
{
    const int idx = blockIdx.x * 256 + threadIdx.x;
    if (idx < HW_ * C_) {                       // sw2t[q][c] = sw2[c][q]
        const int q = idx >> 7, c = idx & 127;
        sw2t[idx] = f2b(sw2[c * HW_ + q]);
    } else if (idx < HW_ * C_ + 3 * C_ * C_) {
        const int r = idx - HW_ * C_;
        const int which = r >> 14, rr = r & 16383;
        const int co = rr >> 7, ci = rr & 127;
        if      (which == 0) gw2t[rr]  = f2b(gw2[ci * C_ + co]);
        else if (which == 1) fw1bt[rr] = f2b(fw1[(529 + ci) * C_ + co]);
        else                 fw2t[rr]  = f2b(fw2[ci * C_ + co]);
    }
}

__global__ __launch_bounds__(256) void k_prep_filt(
    const float* __restrict__ filters, u16* __restrict__ filt)
{
    const int idx = blockIdx.x * 256 + threadIdx.x;   // grid covers 16*128*800
    const int nn = idx / (C_ * 800);
    const int r  = idx % (C_ * 800);
    const int c  = r / 800, q = r % 800;
    filt[idx] = (q < HW_) ? f2b(filters[(nn * C_ + c) * HW_ + q]) : (u16)0;
}

__global__ __launch_bounds__(256) void k_precompute(
    const float* __restrict__ enc_glob, const float* __restrict__ gw1,
    const float* __restrict__ fw1,
    float* __restrict__ glob_gh, float* __restrict__ glob_f1)
{
    const int n = blockIdx.x;
    const int c = threadIdx.x & 127;
    const int which = threadIdx.x >> 7;
    const float* W = which ? fw1 : gw1;
    const float* g = enc_glob + n * G_;
    float acc = 0.f;
    for (int k = 0; k < G_; ++k)
        acc += g[k] * W[(15 + k) * C_ + c];
    (which ? glob_f1 : glob_gh)[n * C_ + c] = acc;
}

// ---------------------------------------------------------------------------
// Main MFMA kernel: 64 points/block, 4 waves, each wave owns 16 points.
// All LDS is per-wave -> no __syncthreads anywhere.
// mfma_f32_16x16x32_bf16 layouts (m89-verified):
//   A: row = lane&15, k = (lane>>4)*8 + j (8 contiguous k per lane)
//   B: col = lane&15, k = (lane>>4)*8 + j
//   C/D: col = lane&15, row = (lane>>4)*4 + reg
// All "transposed" GEMMs put the POINT on the column axis = lane&15, making
// softmax sums / gating / biases lane-local.
// ---------------------------------------------------------------------------
__global__ __launch_bounds__(256) void k_mfma(
    const float* __restrict__ points, const float* __restrict__ transform,
    const float* __restrict__ sw1, const float* __restrict__ sb1,
    const float* __restrict__ sb2,
    const float* __restrict__ gw1, const float* __restrict__ gb1,
    const float* __restrict__ gb2,
    const float* __restrict__ fw1, const float* __restrict__ fb1,
    const float* __restrict__ fb2,
    const float* __restrict__ fw3, const float* __restrict__ fb3,
    const u16* __restrict__ sw2t, const u16* __restrict__ gw2t,
    const u16* __restrict__ fw1bt, const u16* __restrict__ fw2t,
    const u16* __restrict__ filt,
    const float* __restrict__ glob_gh, const float* __restrict__ glob_f1,
    float* __restrict__ out)
{
    __shared__ __align__(16) float s_x [4][16][16];   // per-wave inputs
    __shared__ __align__(16) u16   s_b1[4][16][136];  // sh -> sf -> h2 (pad 136: 2-way free)
    __shared__ __align__(16) u16   s_b2[4][16][136];  // gh -> h1
    __shared__ __align__(16) u16   s_ps[4][16][40];   // P chunk bounce (pad 40)

    const int tid  = threadIdx.x;
    const int wid  = tid >> 6, lane = tid & 63;
    const int l15  = lane & 15, g = lane >> 4;
    const int n    = blockIdx.x >> 6;            // 64 blocks per batch
    const int pblk = (blockIdx.x & 63) << 6;
    const int pw   = pblk + wid * 16;            // wave's first point in batch

    // ---- A1: load x (wave-local) -----------------------------------------
    for (int i = lane; i < 256; i += 64) {
        const int pt = i >> 4, k = i & 15;
        const int gp = n * P_ + pw + pt;
        float v = 0.f;
        if (k < 3)       v = points[gp * 3 + k];
        else if (k < 15) v = transform[gp * 12 + k - 3];
        s_x[wid][pt][k] = v;
    }
    LDS_FENCE();

    // ---- A2: sh (f32 VALU, ->bf16) and gh --------------------------------
    for (int i = lane; i < 2048; i += 64) {
        const int pt = i >> 7, c = i & 127;
        float a1 = sb1[c];
        float a2 = gb1[c] + glob_gh[n * C_ + c];
        #pragma unroll
        for (int k = 0; k < 15; ++k) {
            const float xv = s_x[wid][pt][k];
            a1 += xv * sw1[k * C_ + c];
            a2 += xv * gw1[k * C_ + c];
        }
        s_b1[wid][pt][c] = f2b(fmaxf(a1, 0.f));
        s_b2[wid][pt][c] = f2b(fmaxf(a2, 0.f));
    }
    LDS_FENCE();

    // ---- B: L^T = sw2t . sh^T, exp (no max-sub; logits are small), fused
    //         streaming PV: spatT[c][p] += filt[c][q] * P^T[q][p] ----------
    bf16x8 bsh[4];
    #pragma unroll
    for (int kk = 0; kk < 4; ++kk)
        bsh[kk] = *(const bf16x8*)&s_b1[wid][l15][kk * 32 + 8 * g];

    f32x4 pv[8];
    #pragma unroll
    for (int ct = 0; ct < 8; ++ct) pv[ct] = (f32x4){0.f, 0.f, 0.f, 0.f};
    float psum = 0.f;

    const u16* filtn = filt + (size_t)n * (C_ * 800);

    for (int kt = 0; kt < 25; ++kt) {
        #pragma unroll
        for (int half = 0; half < 2; ++half) {
            const int qt = 2 * kt + half;
            u32 w0 = 0u, w1 = 0u;
            if (qt < 49) {
                const int q0 = qt * 16;
                const u16* ab = sw2t + (size_t)(q0 + l15) * C_ + 8 * g;
                const bf16x8 a0 = *(const bf16x8*)(ab);
                const bf16x8 a1 = *(const bf16x8*)(ab + 32);
                const bf16x8 a2 = *(const bf16x8*)(ab + 64);
                const bf16x8 a3 = *(const bf16x8*)(ab + 96);
                f32x4 c4 = (f32x4){0.f, 0.f, 0.f, 0.f};
                c4 = MFMA(a0, bsh[0], c4);
                c4 = MFMA(a1, bsh[1], c4);
                c4 = MFMA(a2, bsh[2], c4);
                c4 = MFMA(a3, bsh[3], c4);
                const f32x4 bias = *(const f32x4*)(sb2 + q0 + 4 * g);
                const float e0 = __expf(fminf(c4[0] + bias[0], 60.f));
                const float e1 = __expf(fminf(c4[1] + bias[1], 60.f));
                const float e2 = __expf(fminf(c4[2] + bias[2], 60.f));
                const float e3 = __expf(fminf(c4[3] + bias[3], 60.f));
                psum += e0 + e1 + e2 + e3;
                w0 = (u32)f2b(e0) | ((u32)f2b(e1) << 16);
                w1 = (u32)f2b(e2) | ((u32)f2b(e3) << 16);
            }
            u32* dst = (u32*)&s_ps[wid][l15][half * 16 + 4 * g];
            dst[0] = w0; dst[1] = w1;
        }
        LDS_FENCE();
        const bf16x8 bq = *(const bf16x8*)&s_ps[wid][l15][8 * g];
        const u16* fb = filtn + (size_t)l15 * 800 + kt * 32 + 8 * g;
        #pragma unroll
        for (int ct = 0; ct < 8; ++ct) {
            const bf16x8 af = *(const bf16x8*)(fb + ct * 16 * 800);
            pv[ct] = MFMA(af, bq, pv[ct]);
        }
        LDS_FENCE();   // reads done before next chunk overwrites s_ps
    }

    psum += __shfl_xor(psum, 16);
    psum += __shfl_xor(psum, 32);
    const float inv = 1.f / psum;

    // ---- C: gattnT = sigmoid(gw2t . gh^T + gb2); sfT = gattnT*spatT*inv --
    bf16x8 bgh[4];
    #pragma unroll
    for (int kk = 0; kk < 4; ++kk)
        bgh[kk] = *(const bf16x8*)&s_b2[wid][l15][kk * 32 + 8 * g];
    #pragma unroll
    for (int ct = 0; ct < 8; ++ct) {
        f32x4 acc = (f32x4){0.f, 0.f, 0.f, 0.f};
        #pragma unroll
        for (int kk = 0; kk < 4; ++kk) {
            const bf16x8 af = *(const bf16x8*)(gw2t + (size_t)(ct * 16 + l15) * C_ + kk * 32 + 8 * g);
            acc = MFMA(af, bgh[kk], acc);
        }
        const f32x4 gb = *(const f32x4*)(gb2 + ct * 16 + 4 * g);
        const float s0 = pv[ct][0] * inv / (1.f + __expf(-(acc[0] + gb[0])));
        const float s1 = pv[ct][1] * inv / (1.f + __expf(-(acc[1] + gb[1])));
        const float s2 = pv[ct][2] * inv / (1.f + __expf(-(acc[2] + gb[2])));
        const float s3 = pv[ct][3] * inv / (1.f + __expf(-(acc[3] + gb[3])));
        u32* dst = (u32*)&s_b1[wid][l15][ct * 16 + 4 * g];   // sf over sh (dead)
        dst[0] = (u32)f2b(s0) | ((u32)f2b(s1) << 16);
        dst[1] = (u32)f2b(s2) | ((u32)f2b(s3) << 16);
    }
    LDS_FENCE();

    // ---- D: h1T = relu(fw1bt . sf^T + x/coords/glob part) ----------------
    float xr[15];
    #pragma unroll
    for (int k = 0; k < 15; ++k) xr[k] = s_x[wid][l15][k];
    const int pp = pw + l15;
    const float cx = -1.f + 2.f * (float)(pp >> 6) / 63.f;
    const float cy = -1.f + 2.f * (float)(pp & 63) / 63.f;

    bf16x8 bsf[4];
    #pragma unroll
    for (int kk = 0; kk < 4; ++kk)
        bsf[kk] = *(const bf16x8*)&s_b1[wid][l15][kk * 32 + 8 * g];
    #pragma unroll
    for (int ct = 0; ct < 8; ++ct) {
        f32x4 acc = (f32x4){0.f, 0.f, 0.f, 0.f};
        #pragma unroll
        for (int kk = 0; kk < 4; ++kk) {
            const bf16x8 af = *(const bf16x8*)(fw1bt + (size_t)(ct * 16 + l15) * C_ + kk * 32 + 8 * g);
            acc = MFMA(af, bsf[kk], acc);
        }
        f32x4 o = *(const f32x4*)(fb1 + ct * 16 + 4 * g);
        o += *(const f32x4*)(glob_f1 + n * C_ + ct * 16 + 4 * g);
        #pragma unroll
        for (int k = 0; k < 15; ++k)
            o += xr[k] * *(const f32x4*)(fw1 + k * C_ + ct * 16 + 4 * g);
        o += cx * *(const f32x4*)(fw1 + 527 * C_ + ct * 16 + 4 * g);
        o += cy * *(const f32x4*)(fw1 + 528 * C_ + ct * 16 + 4 * g);
        const float h0 = fmaxf(acc[0] + o[0], 0.f);
        const float h1 = fmaxf(acc[1] + o[1], 0.f);
        const float h2 = fmaxf(acc[2] + o[2], 0.f);
        const float h3 = fmaxf(acc[3] + o[3], 0.f);
        u32* dst = (u32*)&s_b2[wid][l15][ct * 16 + 4 * g];   // h1 over gh (dead)
        dst[0] = (u32)f2b(h0) | ((u32)f2b(h1) << 16);
        dst[1] = (u32)f2b(h2) | ((u32)f2b(h3) << 16);
    }
    LDS_FENCE();

    // ---- E: h2T = relu(fw2t . h1^T + fb2) --------------------------------
    bf16x8 bh1[4];
    #pragma unroll
    for (int kk = 0; kk < 4; ++kk)
        bh1[kk] = *(const bf16x8*)&s_b2[wid][l15][kk * 32 + 8 * g];
    #pragma unroll
    for (int ct = 0; ct < 8; ++ct) {
        f32x4 acc = (f32x4){0.f, 0.f, 0.f, 0.f};
        #pragma unroll
        for (int kk = 0; kk < 4; ++kk) {
            const bf16x8 af = *(const bf16x8*)(fw2t + (size_t)(ct * 16 + l15) * C_ + kk * 32 + 8 * g);
            acc = MFMA(af, bh1[kk], acc);
        }
        const f32x4 o = *(const f32x4*)(fb2 + ct * 16 + 4 * g);
        const float h0 = fmaxf(acc[0] + o[0], 0.f);
        const float h1 = fmaxf(acc[1] + o[1], 0.f);
        const float h2 = fmaxf(acc[2] + o[2], 0.f);
        const float h3 = fmaxf(acc[3] + o[3], 0.f);
        u32* dst = (u32*)&s_b1[wid][l15][ct * 16 + 4 * g];   // h2 over sf (dead)
        dst[0] = (u32)f2b(h0) | ((u32)f2b(h1) << 16);
        dst[1] = (u32)f2b(h2) | ((u32)f2b(h3) << 16);
    }
    LDS_FENCE();

    // ---- F: deform = h2 @ fw3 + fb3; out = deform + points ---------------
    if (lane < 48) {
        const int p_loc = lane / 3, d = lane - 3 * p_loc;
        float acc = fb3[d];
        #pragma unroll 8
        for (int c = 0; c < C_; ++c)
            acc += b2f(s_b1[wid][p_loc][c]) * fw3[c * 3 + d];
        const int gp = n * P_ + pw + p_loc;
        out[gp * 3 + d] = acc + s_x[wid][p_loc][d];
    }
}

// ---------------------------------------------------------------------------
// Per-batch normalize in place (f32 output).
// ---------------------------------------------------------------------------
__global__ __launch_bounds__(256) void k_norm(float* __restrict__ out)
{
    __shared__ float red[12];
    const int n = blockIdx.x, tid = threadIdx.x;
    float* p = out + (size_t)n * P_ * 3;

    float sx = 0.f, sy = 0.f, sz = 0.f;
    for (int i = tid; i < P_; i += 256) {
        sx += p[i * 3 + 0]; sy += p[i * 3 + 1]; sz += p[i * 3 + 2];
    }
    #pragma unroll
    for (int m = 32; m >= 1; m >>= 1) {
        sx += __shfl_xor(sx, m); sy += __shfl_xor(sy, m); sz += __shfl_xor(sz, m);
    }
    const int wv = tid >> 6, ln = tid & 63;
    if (ln == 0) { red[wv * 3 + 0] = sx; red[wv * 3 + 1] = sy; red[wv * 3 + 2] = sz; }
    __syncthreads();
    const float meanx = (red[0] + red[3] + red[6] + red[9]) / (float)P_;
    const float meany = (red[1] + red[4] + red[7] + red[10]) / (float)P_;
    const float meanz = (red[2] + red[5] + red[8] + red[11]) / (float)P_;
    __syncthreads();

    float mm = 0.f;
    for (int i = tid; i < P_; i += 256) {
        const float dx = p[i * 3 + 0] - meanx;
        const float dy = p[i * 3 + 1] - meany;
        const float dz = p[i * 3 + 2] - meanz;
        mm = fmaxf(mm, dx * dx + dy * dy + dz * dz);
    }
    #pragma unroll
    for (int m = 32; m >= 1; m >>= 1) mm = fmaxf(mm, __shfl_xor(mm, m));
    if (ln == 0) red[wv] = mm;
    __syncthreads();
    mm = fmaxf(fmaxf(red[0], red[1]), fmaxf(red[2], red[3]));
    const float scale = 1.f / (sqrtf(mm) + 1e-8f);

    for (int i = tid; i < P_; i += 256) {
        p[i * 3 + 0] = (p[i * 3 + 0] - meanx) * scale;
        p[i * 3 + 1] = (p[i * 3 + 1] - meany) * scale;
        p[i * 3 + 2] = (p[i * 3 + 2] - meanz) * scale;
    }
}

// ---------------------------------------------------------------------------
extern "C" void kernel_launch(void* const* d_in, const int* in_sizes, int n_in,
                              void* d_out, int out_size, void* d_ws, size_t ws_size,
                              hipStream_t stream) {
    const float* points    = (const float*)d_in[0];
    const float* transform = (const float*)d_in[1];
    const float* filters   = (const float*)d_in[2];
    const float* enc_glob  = (const float*)d_in[3];
    const float* sw1 = (const float*)d_in[4];
    const float* sb1 = (const float*)d_in[5];
    const float* sw2 = (const float*)d_in[6];
    const float* sb2 = (const float*)d_in[7];
    const float* gw1 = (const float*)d_in[8];
    const float* gb1 = (const float*)d_in[9];
    const float* gw2 = (const float*)d_in[10];
    const float* gb2 = (const float*)d_in[11];
    const float* fw1 = (const float*)d_in[12];
    const float* fb1 = (const float*)d_in[13];
    const float* fw2 = (const float*)d_in[14];
    const float* fb2 = (const float*)d_in[15];
    const float* fw3 = (const float*)d_in[16];
    const float* fb3 = (const float*)d_in[17];

    char* ws = (char*)d_ws;
    float* glob_gh = (float*)(ws + OFF_GLOB_GH);
    float* glob_f1 = (float*)(ws + OFF_GLOB_F1);
    u16*   sw2t    = (u16*)(ws + OFF_SW2T);
    u16*   gw2t    = (u16*)(ws + OFF_GW2T);
    u16*   fw1bt   = (u16*)(ws + OFF_FW1BT);
    u16*   fw2t    = (u16*)(ws + OFF_FW2T);
    u16*   filt    = (u16*)(ws + OFF_FILT);
    float* out     = (float*)d_out;

    k_prep_w<<<(HW_ * C_ + 3 * C_ * C_ + 255) / 256, 256, 0, stream>>>(
        sw2, gw2, fw1, fw2, sw2t, gw2t, fw1bt, fw2t);
    k_prep_filt<<<(N_ * C_ * 800) / 256, 256, 0, stream>>>(filters, filt);
    k_precompute<<<N_, 256, 0, stream>>>(enc_glob, gw1, fw1, glob_gh, glob_f1);
    k_mfma<<<N_ * (P_ / 64), 256, 0, stream>>>(
        points, transform, sw1, sb1, sb2, gw1, gb1, gb2,
        fw1, fb1, fb2, fw3, fb3,
        sw2t, gw2t, fw1bt, fw2t, filt, glob_gh, glob_f1, out);
    k_norm<<<N_, 256, 0, stream>>>(out);
}

// Round 7
// 349.763 us; speedup vs baseline: 9.9541x; 1.0647x over previous
//
#include <hip/hip_runtime.h>
#include <hip/hip_bf16.h>

#define N_   16
#define P_   4096
#define C_   128
#define HW_  784
#define G_   512

typedef unsigned short u16;
typedef unsigned int   u32;
typedef __attribute__((ext_vector_type(8))) short bf16x8;
typedef __attribute__((ext_vector_type(4))) float f32x4;

union B8 { bf16x8 v; u32 w[4]; };

#define MFMA(a,b,c) __builtin_amdgcn_mfma_f32_16x16x32_bf16((a),(b),(c),0,0,0)

__device__ __forceinline__ u16 f2b(float f) {
    __hip_bfloat16 h = __float2bfloat16(f);
    return *reinterpret_cast<u16*>(&h);
}
__device__ __forceinline__ u32 pk(float lo, float hi) {
    return (u32)f2b(lo) | ((u32)f2b(hi) << 16);
}

// ---------------------------------------------------------------------------
// ws layout (bytes). All bf16 A-operand matrices are stored with their
// M-dim rows PERMUTED so that MFMA D-layout (row=4g+reg per 16-tile pair)
// lands exactly in B-fragment k-order (k=8g+j per 32-block):
//   row position (16ct + r)  holds true index 32*(ct>>1) + 8*(r>>2) + 4*(ct&1) + (r&3)
// f32 side-arrays (biases, glob, fw1 rows) need NO copies: lane loads f32x4
// at c_base = 32*(ct>>1) + 8g + 4*(ct&1), which is the true index base.
// ---------------------------------------------------------------------------
#define OFF_SW2P    0         // 800x128 bf16 (q rows permuted, q>=784 zero)
#define OFF_SW1P    204800    // 128x32 bf16 (out-c permuted, k>=15 zero)
#define OFF_GW1P    212992    // 128x32 bf16
#define OFF_GW2P    221184    // 128x128 bf16 (out-c permuted)
#define OFF_FW1BP   253952    // 128x128 bf16 (out-c permuted, fw1 rows 529+)
#define OFF_FW2P    286720    // 128x128 bf16 (out-c permuted)
#define OFF_SB2P    319488    // 800 f32 (plain order, q>=784 = -1e30)
#define OFF_GLOBGH  322688    // 16x128 f32 (plain)
#define OFF_GLOBF1  330880    // 16x128 f32 (plain)
#define OFF_FILTP   339072    // 16x128x800 bf16 (c rows permuted, q>=784 zero)

// segment boundaries (flat thread index) for the fused prep kernel
#define SG0 102400    // end sw2p
#define SG1 110592    // end sw1p
#define SG2 118784    // end gw1p
#define SG3 135168    // end gw2p
#define SG4 151552    // end fw1bp
#define SG5 167936    // end fw2p
#define SG6 168736    // end sb2p
#define SG7 1807136   // end filtp
#define SG8 1811232   // end glob precompute

__device__ __forceinline__ int perm_c(int row) {   // row pos -> true index
    const int ct = row >> 4, r = row & 15;
    return 32 * (ct >> 1) + 8 * (r >> 2) + 4 * (ct & 1) + (r & 3);
}

// ---------------------------------------------------------------------------
__global__ __launch_bounds__(256) void k_prep(
    const float* __restrict__ sw1, const float* __restrict__ sw2,
    const float* __restrict__ sb2, const float* __restrict__ gw1,
    const float* __restrict__ gw2, const float* __restrict__ fw1,
    const float* __restrict__ fw2, const float* __restrict__ filters,
    const float* __restrict__ enc_glob,
    u16* __restrict__ sw2p, u16* __restrict__ sw1p, u16* __restrict__ gw1p,
    u16* __restrict__ gw2p, u16* __restrict__ fw1bp, u16* __restrict__ fw2p,
    float* __restrict__ sb2p, u16* __restrict__ filtp,
    float* __restrict__ glob_gh, float* __restrict__ glob_f1)
{
    const int idx = blockIdx.x * 256 + threadIdx.x;
    if (idx < SG0) {                      // sw2p: q-rows permuted per 32-block
        const int r_new = idx >> 7, c = idx & 127;
        const int kt = r_new >> 5, o = r_new & 31, h = (o >> 4) & 1, r = o & 15;
        const int q = kt * 32 + 8 * (r >> 2) + 4 * h + (r & 3);
        sw2p[idx] = (q < HW_) ? f2b(sw2[c * HW_ + q]) : (u16)0;
    } else if (idx < SG1) {               // sw1p
        const int t = idx - SG0;
        const int row = t >> 5, k = t & 31;
        const int c = perm_c(row);
        sw1p[t] = (k < 15) ? f2b(sw1[k * C_ + c]) : (u16)0;
    } else if (idx < SG2) {               // gw1p
        const int t = idx - SG1;
        const int row = t >> 5, k = t & 31;
        const int c = perm_c(row);
        gw1p[t] = (k < 15) ? f2b(gw1[k * C_ + c]) : (u16)0;
    } else if (idx < SG3) {               // gw2p
        const int t = idx - SG2;
        const int row = t >> 7, ci = t & 127;
        gw2p[t] = f2b(gw2[ci * C_ + perm_c(row)]);
    } else if (idx < SG4) {               // fw1bp (fw1 rows 529..656)
        const int t = idx - SG3;
        const int row = t >> 7, ci = t & 127;
        fw1bp[t] = f2b(fw1[(529 + ci) * C_ + perm_c(row)]);
    } else if (idx < SG5) {               // fw2p
        const int t = idx - SG4;
        const int row = t >> 7, ci = t & 127;
        fw2p[t] = f2b(fw2[ci * C_ + perm_c(row)]);
    } else if (idx < SG6) {               // sb2p: plain order + -inf tail
        const int q = idx - SG5;
        sb2p[q] = (q < HW_) ? sb2[q] : -1e30f;
    } else if (idx < SG7) {               // filtp: c-rows permuted, q padded
        const int t = idx - SG6;
        const int nn = t / 102400;
        const int rr = t % 102400;
        const int row = rr / 800, q = rr % 800;
        const int c = perm_c(row);
        filtp[t] = (q < HW_) ? f2b(filters[((size_t)nn * C_ + c) * HW_ + q]) : (u16)0;
    } else if (idx < SG8) {               // glob_gh / glob_f1 (plain layout)
        const int t = idx - SG7;
        const int which = t >> 11;
        const int nn = (t >> 7) & 15, c = t & 127;
        const float* W = which ? fw1 : gw1;
        const float* gv = enc_glob + nn * G_;
        float acc = 0.f;
        for (int k = 0; k < G_; ++k)
            acc += gv[k] * W[(15 + k) * C_ + c];
        (which ? glob_f1 : glob_gh)[nn * C_ + c] = acc;
    }
}

// ---------------------------------------------------------------------------
// Main kernel: 64 points/block, 4 waves, 16 points/wave. Everything except
// s_x (4 KB) is register-resident; the kt loop has NO LDS/fences, so the
// compiler can pipeline global loads across iterations.
// ---------------------------------------------------------------------------
__global__ __launch_bounds__(256, 4) void k_mfma(
    const float* __restrict__ points, const float* __restrict__ transform,
    const float* __restrict__ sb1, const float* __restrict__ gb1,
    const float* __restrict__ gb2, const float* __restrict__ fb1,
    const float* __restrict__ fb2, const float* __restrict__ fb3,
    const float* __restrict__ fw1, const float* __restrict__ fw3,
    const u16* __restrict__ sw1p, const u16* __restrict__ gw1p,
    const u16* __restrict__ sw2p, const float* __restrict__ sb2p,
    const u16* __restrict__ gw2p, const u16* __restrict__ fw1bp,
    const u16* __restrict__ fw2p, const u16* __restrict__ filtp,
    const float* __restrict__ glob_gh, const float* __restrict__ glob_f1,
    float* __restrict__ out)
{
    __shared__ __align__(16) float s_x[4][16][16];

    const int tid = threadIdx.x, wid = tid >> 6, lane = tid & 63;
    const int p = lane & 15, g = lane >> 4;
    const int n = blockIdx.x >> 6;
    const int pw = ((blockIdx.x & 63) << 6) + (wid << 4);

    // ---- A1: inputs to LDS (per-wave) ------------------------------------
    for (int i = lane; i < 256; i += 64) {
        const int pt = i >> 4, k = i & 15;
        const int gp = n * P_ + pw + pt;
        float v = 0.f;
        if (k < 3)       v = points[gp * 3 + k];
        else if (k < 15) v = transform[gp * 12 + k - 3];
        s_x[wid][pt][k] = v;
    }
    asm volatile("s_waitcnt lgkmcnt(0)" ::: "memory");
    __builtin_amdgcn_sched_barrier(0);

    // ---- x as B-fragment (k = 8g+j; k>=15 hits zero A rows) --------------
    B8 bx; bx.w[0] = bx.w[1] = bx.w[2] = bx.w[3] = 0u;
    if (g < 2) {
        const float* xs = &s_x[wid][p][8 * g];
        bx.w[0] = pk(xs[0], xs[1]); bx.w[1] = pk(xs[2], xs[3]);
        bx.w[2] = pk(xs[4], xs[5]); bx.w[3] = pk(xs[6], xs[7]);
    }

    // ---- A2: sh, gh via MFMA (outputs land directly in B-frag order) -----
    B8 bsh[4], bgh[4];
    #pragma unroll
    for (int ct = 0; ct < 8; ++ct) {
        const bf16x8 a_s = *(const bf16x8*)(sw1p + (16 * ct + p) * 32 + 8 * g);
        const bf16x8 a_g = *(const bf16x8*)(gw1p + (16 * ct + p) * 32 + 8 * g);
        f32x4 cs = (f32x4){0.f, 0.f, 0.f, 0.f};
        f32x4 cg = (f32x4){0.f, 0.f, 0.f, 0.f};
        cs = MFMA(a_s, bx.v, cs);
        cg = MFMA(a_g, bx.v, cg);
        const int cb = 32 * (ct >> 1) + 8 * g + 4 * (ct & 1);
        const f32x4 b1 = *(const f32x4*)(sb1 + cb);
        const f32x4 b2 = *(const f32x4*)(gb1 + cb);
        const f32x4 gg = *(const f32x4*)(glob_gh + n * C_ + cb);
        const float sh0 = fmaxf(cs[0] + b1[0], 0.f), sh1 = fmaxf(cs[1] + b1[1], 0.f);
        const float sh2 = fmaxf(cs[2] + b1[2], 0.f), sh3 = fmaxf(cs[3] + b1[3], 0.f);
        const float gh0 = fmaxf(cg[0] + b2[0] + gg[0], 0.f), gh1 = fmaxf(cg[1] + b2[1] + gg[1], 0.f);
        const float gh2 = fmaxf(cg[2] + b2[2] + gg[2], 0.f), gh3 = fmaxf(cg[3] + b2[3] + gg[3], 0.f);
        const int m = ct >> 1, o = (ct & 1) * 2;
        bsh[m].w[o] = pk(sh0, sh1); bsh[m].w[o + 1] = pk(sh2, sh3);
        bgh[m].w[o] = pk(gh0, gh1); bgh[m].w[o + 1] = pk(gh2, gh3);
    }

    // ---- B: logits -> exp -> fused PV, all register-resident -------------
    f32x4 pv[8];
    #pragma unroll
    for (int ct = 0; ct < 8; ++ct) pv[ct] = (f32x4){0.f, 0.f, 0.f, 0.f};
    float psum = 0.f;
    const u16* filtn = filtp + (size_t)n * (C_ * 800);

    for (int kt = 0; kt < 25; ++kt) {
        B8 bq;
        #pragma unroll
        for (int h = 0; h < 2; ++h) {
            const u16* ar = sw2p + (size_t)(32 * kt + 16 * h + p) * C_ + 8 * g;
            f32x4 c4 = (f32x4){0.f, 0.f, 0.f, 0.f};
            c4 = MFMA(*(const bf16x8*)(ar),      bsh[0].v, c4);
            c4 = MFMA(*(const bf16x8*)(ar + 32), bsh[1].v, c4);
            c4 = MFMA(*(const bf16x8*)(ar + 64), bsh[2].v, c4);
            c4 = MFMA(*(const bf16x8*)(ar + 96), bsh[3].v, c4);
            const f32x4 bi = *(const f32x4*)(sb2p + 32 * kt + 8 * g + 4 * h);
            const float e0 = __expf(fminf(c4[0] + bi[0], 60.f));
            const float e1 = __expf(fminf(c4[1] + bi[1], 60.f));
            const float e2 = __expf(fminf(c4[2] + bi[2], 60.f));
            const float e3 = __expf(fminf(c4[3] + bi[3], 60.f));
            psum += (e0 + e1) + (e2 + e3);
            bq.w[2 * h + 0] = pk(e0, e1);
            bq.w[2 * h + 1] = pk(e2, e3);
        }
        const u16* fr = filtn + (size_t)p * 800 + 32 * kt + 8 * g;
        #pragma unroll
        for (int ct = 0; ct < 8; ++ct) {
            const bf16x8 af = *(const bf16x8*)(fr + (size_t)ct * 16 * 800);
            pv[ct] = MFMA(af, bq.v, pv[ct]);
        }
    }
    psum += __shfl_xor(psum, 16);
    psum += __shfl_xor(psum, 32);
    const float inv = 1.f / psum;

    // ---- C: gattn = sigmoid(gw2.gh + gb2); sf = gattn * pv * inv ---------
    B8 bsf[4];
    #pragma unroll
    for (int ct = 0; ct < 8; ++ct) {
        const u16* ar = gw2p + (16 * ct + p) * C_ + 8 * g;
        f32x4 acc = (f32x4){0.f, 0.f, 0.f, 0.f};
        acc = MFMA(*(const bf16x8*)(ar),      bgh[0].v, acc);
        acc = MFMA(*(const bf16x8*)(ar + 32), bgh[1].v, acc);
        acc = MFMA(*(const bf16x8*)(ar + 64), bgh[2].v, acc);
        acc = MFMA(*(const bf16x8*)(ar + 96), bgh[3].v, acc);
        const int cb = 32 * (ct >> 1) + 8 * g + 4 * (ct & 1);
        const f32x4 gb = *(const f32x4*)(gb2 + cb);
        const float s0 = pv[ct][0] * inv / (1.f + __expf(-(acc[0] + gb[0])));
        const float s1 = pv[ct][1] * inv / (1.f + __expf(-(acc[1] + gb[1])));
        const float s2 = pv[ct][2] * inv / (1.f + __expf(-(acc[2] + gb[2])));
        const float s3 = pv[ct][3] * inv / (1.f + __expf(-(acc[3] + gb[3])));
        const int m = ct >> 1, o = (ct & 1) * 2;
        bsf[m].w[o] = pk(s0, s1); bsf[m].w[o + 1] = pk(s2, s3);
    }

    // ---- D: h1 = relu(fw1b.sf + f32 side terms) --------------------------
    float xr[15];
    #pragma unroll
    for (int k = 0; k < 15; ++k) xr[k] = s_x[wid][p][k];
    const int pp = pw + p;
    const float cx = -1.f + 2.f * (float)(pp >> 6) / 63.f;
    const float cy = -1.f + 2.f * (float)(pp & 63) / 63.f;

    B8 bh1[4];
    #pragma unroll
    for (int ct = 0; ct < 8; ++ct) {
        const u16* ar = fw1bp + (16 * ct + p) * C_ + 8 * g;
        f32x4 acc = (f32x4){0.f, 0.f, 0.f, 0.f};
        acc = MFMA(*(const bf16x8*)(ar),      bsf[0].v, acc);
        acc = MFMA(*(const bf16x8*)(ar + 32), bsf[1].v, acc);
        acc = MFMA(*(const bf16x8*)(ar + 64), bsf[2].v, acc);
        acc = MFMA(*(const bf16x8*)(ar + 96), bsf[3].v, acc);
        const int cb = 32 * (ct >> 1) + 8 * g + 4 * (ct & 1);
        f32x4 o4 = *(const f32x4*)(fb1 + cb);
        o4 += *(const f32x4*)(glob_f1 + n * C_ + cb);
        #pragma unroll
        for (int k = 0; k < 15; ++k)
            o4 += xr[k] * *(const f32x4*)(fw1 + k * C_ + cb);
        o4 += cx * *(const f32x4*)(fw1 + 527 * C_ + cb);
        o4 += cy * *(const f32x4*)(fw1 + 528 * C_ + cb);
        const float h0 = fmaxf(acc[0] + o4[0], 0.f), h1v = fmaxf(acc[1] + o4[1], 0.f);
        const float h2 = fmaxf(acc[2] + o4[2], 0.f), h3 = fmaxf(acc[3] + o4[3], 0.f);
        const int m = ct >> 1, o = (ct & 1) * 2;
        bh1[m].w[o] = pk(h0, h1v); bh1[m].w[o + 1] = pk(h2, h3);
    }

    // ---- E: h2 = relu(fw2.h1 + fb2), kept f32 in registers ---------------
    float h2r[8][4];
    #pragma unroll
    for (int ct = 0; ct < 8; ++ct) {
        const u16* ar = fw2p + (16 * ct + p) * C_ + 8 * g;
        f32x4 acc = (f32x4){0.f, 0.f, 0.f, 0.f};
        acc = MFMA(*(const bf16x8*)(ar),      bh1[0].v, acc);
        acc = MFMA(*(const bf16x8*)(ar + 32), bh1[1].v, acc);
        acc = MFMA(*(const bf16x8*)(ar + 64), bh1[2].v, acc);
        acc = MFMA(*(const bf16x8*)(ar + 96), bh1[3].v, acc);
        const int cb = 32 * (ct >> 1) + 8 * g + 4 * (ct & 1);
        const f32x4 o4 = *(const f32x4*)(fb2 + cb);
        #pragma unroll
        for (int r = 0; r < 4; ++r) h2r[ct][r] = fmaxf(acc[r] + o4[r], 0.f);
    }

    // ---- F: deform = h2 @ fw3; reduce across the 4 lane-groups -----------
    float d0 = 0.f, d1 = 0.f, d2 = 0.f;
    #pragma unroll
    for (int ct = 0; ct < 8; ++ct) {
        const int cb = 32 * (ct >> 1) + 8 * g + 4 * (ct & 1);
        #pragma unroll
        for (int r = 0; r < 4; ++r) {
            const float h = h2r[ct][r];
            const float* w3 = fw3 + (cb + r) * 3;
            d0 += h * w3[0]; d1 += h * w3[1]; d2 += h * w3[2];
        }
    }
    d0 += __shfl_xor(d0, 16); d0 += __shfl_xor(d0, 32);
    d1 += __shfl_xor(d1, 16); d1 += __shfl_xor(d1, 32);
    d2 += __shfl_xor(d2, 16); d2 += __shfl_xor(d2, 32);
    if (g == 0) {
        const int gp = n * P_ + pw + p;
        out[gp * 3 + 0] = d0 + fb3[0] + s_x[wid][p][0];
        out[gp * 3 + 1] = d1 + fb3[1] + s_x[wid][p][1];
        out[gp * 3 + 2] = d2 + fb3[2] + s_x[wid][p][2];
    }
}

// ---------------------------------------------------------------------------
// Per-batch normalize in place (f32), 1024 threads.
// ---------------------------------------------------------------------------
__global__ __launch_bounds__(1024) void k_norm(float* __restrict__ out)
{
    __shared__ float red[48];
    __shared__ float red2[16];
    const int n = blockIdx.x, tid = threadIdx.x;
    float* pb = out + (size_t)n * P_ * 3;

    float sx = 0.f, sy = 0.f, sz = 0.f;
    for (int i = tid; i < P_; i += 1024) {
        sx += pb[i * 3 + 0]; sy += pb[i * 3 + 1]; sz += pb[i * 3 + 2];
    }
    #pragma unroll
    for (int m = 32; m >= 1; m >>= 1) {
        sx += __shfl_xor(sx, m); sy += __shfl_xor(sy, m); sz += __shfl_xor(sz, m);
    }
    const int wv = tid >> 6, ln = tid & 63;
    if (ln == 0) { red[wv * 3 + 0] = sx; red[wv * 3 + 1] = sy; red[wv * 3 + 2] = sz; }
    __syncthreads();
    float meanx = 0.f, meany = 0.f, meanz = 0.f;
    #pragma unroll
    for (int w = 0; w < 16; ++w) {
        meanx += red[w * 3 + 0]; meany += red[w * 3 + 1]; meanz += red[w * 3 + 2];
    }
    meanx /= (float)P_; meany /= (float)P_; meanz /= (float)P_;

    float mm = 0.f;
    for (int i = tid; i < P_; i += 1024) {
        const float dx = pb[i * 3 + 0] - meanx;
        const float dy = pb[i * 3 + 1] - meany;
        const float dz = pb[i * 3 + 2] - meanz;
        mm = fmaxf(mm, dx * dx + dy * dy + dz * dz);
    }
    #pragma unroll
    for (int m = 32; m >= 1; m >>= 1) mm = fmaxf(mm, __shfl_xor(mm, m));
    if (ln == 0) red2[wv] = mm;
    __syncthreads();
    mm = 0.f;
    #pragma unroll
    for (int w = 0; w < 16; ++w) mm = fmaxf(mm, red2[w]);
    const float scale = 1.f / (sqrtf(mm) + 1e-8f);

    for (int i = tid; i < P_; i += 1024) {
        pb[i * 3 + 0] = (pb[i * 3 + 0] - meanx) * scale;
        pb[i * 3 + 1] = (pb[i * 3 + 1] - meany) * scale;
        pb[i * 3 + 2] = (pb[i * 3 + 2] - meanz) * scale;
    }
}

// ---------------------------------------------------------------------------
extern "C" void kernel_launch(void* const* d_in, const int* in_sizes, int n_in,
                              void* d_out, int out_size, void* d_ws, size_t ws_size,
                              hipStream_t stream) {
    const float* points    = (const float*)d_in[0];
    const float* transform = (const float*)d_in[1];
    const float* filters   = (const float*)d_in[2];
    const float* enc_glob  = (const float*)d_in[3];
    const float* sw1 = (const float*)d_in[4];
    const float* sb1 = (const float*)d_in[5];
    const float* sw2 = (const float*)d_in[6];
    const float* sb2 = (const float*)d_in[7];
    const float* gw1 = (const float*)d_in[8];
    const float* gb1 = (const float*)d_in[9];
    const float* gw2 = (const float*)d_in[10];
    const float* gb2 = (const float*)d_in[11];
    const float* fw1 = (const float*)d_in[12];
    const float* fb1 = (const float*)d_in[13];
    const float* fw2 = (const float*)d_in[14];
    const float* fb2 = (const float*)d_in[15];
    const float* fw3 = (const float*)d_in[16];
    const float* fb3 = (const float*)d_in[17];

    char* ws = (char*)d_ws;
    u16*   sw2p    = (u16*)(ws + OFF_SW2P);
    u16*   sw1p    = (u16*)(ws + OFF_SW1P);
    u16*   gw1p    = (u16*)(ws + OFF_GW1P);
    u16*   gw2p    = (u16*)(ws + OFF_GW2P);
    u16*   fw1bp   = (u16*)(ws + OFF_FW1BP);
    u16*   fw2p    = (u16*)(ws + OFF_FW2P);
    float* sb2p    = (float*)(ws + OFF_SB2P);
    float* glob_gh = (float*)(ws + OFF_GLOBGH);
    float* glob_f1 = (float*)(ws + OFF_GLOBF1);
    u16*   filtp   = (u16*)(ws + OFF_FILTP);
    float* out     = (float*)d_out;

    k_prep<<<(SG8 + 255) / 256, 256, 0, stream>>>(
        sw1, sw2, sb2, gw1, gw2, fw1, fw2, filters, enc_glob,
        sw2p, sw1p, gw1p, gw2p, fw1bp, fw2p, sb2p, filtp, glob_gh, glob_f1);
    k_mfma<<<N_ * (P_ / 64), 256, 0, stream>>>(
        points, transform, sb1, gb1, gb2, fb1, fb2, fb3, fw1, fw3,
        sw1p, gw1p, sw2p, sb2p, gw2p, fw1bp, fw2p, filtp,
        glob_gh, glob_f1, out);
    k_norm<<<N_, 1024, 0, stream>>>(out);
}

// Round 8
// 328.286 us; speedup vs baseline: 10.6053x; 1.0654x over previous
//
#include <hip/hip_runtime.h>
#include <hip/hip_bf16.h>

#define N_   16
#define P_   4096
#define C_   128
#define HW_  784
#define G_   512

typedef unsigned short u16;
typedef unsigned int   u32;
typedef __attribute__((ext_vector_type(8))) short bf16x8;
typedef __attribute__((ext_vector_type(4))) float f32x4;

union B8 { bf16x8 v; u32 w[4]; };

#define MFMA(a,b,c) __builtin_amdgcn_mfma_f32_16x16x32_bf16((a),(b),(c),0,0,0)

__device__ __forceinline__ u16 f2b(float f) {
    __hip_bfloat16 h = __float2bfloat16(f);
    return *reinterpret_cast<u16*>(&h);
}
__device__ __forceinline__ u32 pk(float lo, float hi) {
    return (u32)f2b(lo) | ((u32)f2b(hi) << 16);
}

// ---------------------------------------------------------------------------
// ws layout (bytes). All bf16 A-operand matrices are stored with their
// M-dim rows PERMUTED so that MFMA D-layout (row=4g+reg per 16-tile pair)
// lands exactly in B-fragment k-order (k=8g+j per 32-block):
//   row position (16ct + r)  holds true index 32*(ct>>1) + 8*(r>>2) + 4*(ct&1) + (r&3)
// f32 side-arrays (biases, glob, fw1 rows) need NO copies: lane loads f32x4
// at c_base = 32*(ct>>1) + 8g + 4*(ct&1), which is the true index base.
// ---------------------------------------------------------------------------
#define OFF_SW2P    0         // 800x128 bf16 (q rows permuted, q>=784 zero)
#define OFF_SW1P    204800    // 128x32 bf16 (out-c permuted, k>=15 zero)
#define OFF_GW1P    212992    // 128x32 bf16
#define OFF_GW2P    221184    // 128x128 bf16 (out-c permuted)
#define OFF_FW1BP   253952    // 128x128 bf16 (out-c permuted, fw1 rows 529+)
#define OFF_FW2P    286720    // 128x128 bf16 (out-c permuted)
#define OFF_SB2P    319488    // 800 f32 (plain order, q>=784 = -1e30)
#define OFF_GLOBGH  322688    // 16x128 f32 (plain)
#define OFF_GLOBF1  330880    // 16x128 f32 (plain)
#define OFF_FILTP   339072    // 16x128x800 bf16 (c rows permuted, q>=784 zero)

// segment boundaries (flat thread index) for the fused prep kernel
#define SG0 102400    // end sw2p
#define SG1 110592    // end sw1p
#define SG2 118784    // end gw1p
#define SG3 135168    // end gw2p
#define SG4 151552    // end fw1bp
#define SG5 167936    // end fw2p
#define SG6 168736    // end sb2p
#define SG7 1807136   // end filtp
#define SG8 1811232   // end glob precompute

__device__ __forceinline__ int perm_c(int row) {   // row pos -> true index
    const int ct = row >> 4, r = row & 15;
    return 32 * (ct >> 1) + 8 * (r >> 2) + 4 * (ct & 1) + (r & 3);
}

// ---------------------------------------------------------------------------
__global__ __launch_bounds__(256) void k_prep(
    const float* __restrict__ sw1, const float* __restrict__ sw2,
    const float* __restrict__ sb2, const float* __restrict__ gw1,
    const float* __restrict__ gw2, const float* __restrict__ fw1,
    const float* __restrict__ fw2, const float* __restrict__ filters,
    const float* __restrict__ enc_glob,
    u16* __restrict__ sw2p, u16* __restrict__ sw1p, u16* __restrict__ gw1p,
    u16* __restrict__ gw2p, u16* __restrict__ fw1bp, u16* __restrict__ fw2p,
    float* __restrict__ sb2p, u16* __restrict__ filtp,
    float* __restrict__ glob_gh, float* __restrict__ glob_f1)
{
    const int idx = blockIdx.x * 256 + threadIdx.x;
    if (idx < SG0) {                      // sw2p: q-rows permuted per 32-block
        const int r_new = idx >> 7, c = idx & 127;
        const int kt = r_new >> 5, o = r_new & 31, h = (o >> 4) & 1, r = o & 15;
        const int q = kt * 32 + 8 * (r >> 2) + 4 * h + (r & 3);
        sw2p[idx] = (q < HW_) ? f2b(sw2[c * HW_ + q]) : (u16)0;
    } else if (idx < SG1) {               // sw1p
        const int t = idx - SG0;
        const int row = t >> 5, k = t & 31;
        const int c = perm_c(row);
        sw1p[t] = (k < 15) ? f2b(sw1[k * C_ + c]) : (u16)0;
    } else if (idx < SG2) {               // gw1p
        const int t = idx - SG1;
        const int row = t >> 5, k = t & 31;
        const int c = perm_c(row);
        gw1p[t] = (k < 15) ? f2b(gw1[k * C_ + c]) : (u16)0;
    } else if (idx < SG3) {               // gw2p
        const int t = idx - SG2;
        const int row = t >> 7, ci = t & 127;
        gw2p[t] = f2b(gw2[ci * C_ + perm_c(row)]);
    } else if (idx < SG4) {               // fw1bp (fw1 rows 529..656)
        const int t = idx - SG3;
        const int row = t >> 7, ci = t & 127;
        fw1bp[t] = f2b(fw1[(529 + ci) * C_ + perm_c(row)]);
    } else if (idx < SG5) {               // fw2p
        const int t = idx - SG4;
        const int row = t >> 7, ci = t & 127;
        fw2p[t] = f2b(fw2[ci * C_ + perm_c(row)]);
    } else if (idx < SG6) {               // sb2p: plain order + -inf tail
        const int q = idx - SG5;
        sb2p[q] = (q < HW_) ? sb2[q] : -1e30f;
    } else if (idx < SG7) {               // filtp: c-rows permuted, q padded
        const int t = idx - SG6;
        const int nn = t / 102400;
        const int rr = t % 102400;
        const int row = rr / 800, q = rr % 800;
        const int c = perm_c(row);
        filtp[t] = (q < HW_) ? f2b(filters[((size_t)nn * C_ + c) * HW_ + q]) : (u16)0;
    } else if (idx < SG8) {               // glob_gh / glob_f1 (plain layout)
        const int t = idx - SG7;
        const int which = t >> 11;
        const int nn = (t >> 7) & 15, c = t & 127;
        const float* W = which ? fw1 : gw1;
        const float* gv = enc_glob + nn * G_;
        float acc = 0.f;
        for (int k = 0; k < G_; ++k)
            acc += gv[k] * W[(15 + k) * C_ + c];
        (which ? glob_f1 : glob_gh)[nn * C_ + c] = acc;
    }
}

// ---------------------------------------------------------------------------
// Main kernel: 64 points/block, 4 waves, 16 points/wave. Everything except
// s_x (4 KB) is register-resident; the kt loop has NO LDS/fences, so the
// compiler can pipeline global loads across iterations.
// Plain __launch_bounds__(256): round-7's (256,4) capped VGPR+AGPR at 128
// and caused 87 MB of scratch spill traffic (WRITE_SIZE counter).
// bgh is recomputed AFTER the kt loop (bx is 4 regs vs bgh's 16) to shrink
// loop-B live state.
// ---------------------------------------------------------------------------
__global__ __launch_bounds__(256) void k_mfma(
    const float* __restrict__ points, const float* __restrict__ transform,
    const float* __restrict__ sb1, const float* __restrict__ gb1,
    const float* __restrict__ gb2, const float* __restrict__ fb1,
    const float* __restrict__ fb2, const float* __restrict__ fb3,
    const float* __restrict__ fw1, const float* __restrict__ fw3,
    const u16* __restrict__ sw1p, const u16* __restrict__ gw1p,
    const u16* __restrict__ sw2p, const float* __restrict__ sb2p,
    const u16* __restrict__ gw2p, const u16* __restrict__ fw1bp,
    const u16* __restrict__ fw2p, const u16* __restrict__ filtp,
    const float* __restrict__ glob_gh, const float* __restrict__ glob_f1,
    float* __restrict__ out)
{
    __shared__ __align__(16) float s_x[4][16][16];

    const int tid = threadIdx.x, wid = tid >> 6, lane = tid & 63;
    const int p = lane & 15, g = lane >> 4;
    // XCD-aware swizzle: consecutive hardware bids round-robin XCDs; remap so
    // each XCD sees a contiguous 128-block chunk => only 2 distinct n per XCD
    // (filt working set 0.4 MB << 4 MB L2). 1024 % 8 == 0 -> bijective.
    const int bid = blockIdx.x;
    const int nb  = (bid & 7) * 128 + (bid >> 3);
    const int n   = nb >> 6;
    const int pw  = ((nb & 63) << 6) + (wid << 4);

    // ---- A1: inputs to LDS (per-wave) ------------------------------------
    for (int i = lane; i < 256; i += 64) {
        const int pt = i >> 4, k = i & 15;
        const int gp = n * P_ + pw + pt;
        float v = 0.f;
        if (k < 3)       v = points[gp * 3 + k];
        else if (k < 15) v = transform[gp * 12 + k - 3];
        s_x[wid][pt][k] = v;
    }
    asm volatile("s_waitcnt lgkmcnt(0)" ::: "memory");
    __builtin_amdgcn_sched_barrier(0);

    // ---- x as B-fragment (k = 8g+j; k>=15 hits zero A rows) --------------
    B8 bx; bx.w[0] = bx.w[1] = bx.w[2] = bx.w[3] = 0u;
    if (g < 2) {
        const float* xs = &s_x[wid][p][8 * g];
        bx.w[0] = pk(xs[0], xs[1]); bx.w[1] = pk(xs[2], xs[3]);
        bx.w[2] = pk(xs[4], xs[5]); bx.w[3] = pk(xs[6], xs[7]);
    }

    // ---- A2: sh via MFMA (output lands directly in B-frag order) ---------
    B8 bsh[4];
    #pragma unroll
    for (int ct = 0; ct < 8; ++ct) {
        const bf16x8 a_s = *(const bf16x8*)(sw1p + (16 * ct + p) * 32 + 8 * g);
        f32x4 cs = (f32x4){0.f, 0.f, 0.f, 0.f};
        cs = MFMA(a_s, bx.v, cs);
        const int cb = 32 * (ct >> 1) + 8 * g + 4 * (ct & 1);
        const f32x4 b1 = *(const f32x4*)(sb1 + cb);
        const float sh0 = fmaxf(cs[0] + b1[0], 0.f), sh1 = fmaxf(cs[1] + b1[1], 0.f);
        const float sh2 = fmaxf(cs[2] + b1[2], 0.f), sh3 = fmaxf(cs[3] + b1[3], 0.f);
        const int m = ct >> 1, o = (ct & 1) * 2;
        bsh[m].w[o] = pk(sh0, sh1); bsh[m].w[o + 1] = pk(sh2, sh3);
    }

    // ---- B: logits -> exp -> fused PV, all register-resident -------------
    f32x4 pv[8];
    #pragma unroll
    for (int ct = 0; ct < 8; ++ct) pv[ct] = (f32x4){0.f, 0.f, 0.f, 0.f};
    float psum = 0.f;
    const u16* filtn = filtp + (size_t)n * (C_ * 800);

    for (int kt = 0; kt < 25; ++kt) {
        B8 bq;
        #pragma unroll
        for (int h = 0; h < 2; ++h) {
            const u16* ar = sw2p + (size_t)(32 * kt + 16 * h + p) * C_ + 8 * g;
            f32x4 c4 = (f32x4){0.f, 0.f, 0.f, 0.f};
            c4 = MFMA(*(const bf16x8*)(ar),      bsh[0].v, c4);
            c4 = MFMA(*(const bf16x8*)(ar + 32), bsh[1].v, c4);
            c4 = MFMA(*(const bf16x8*)(ar + 64), bsh[2].v, c4);
            c4 = MFMA(*(const bf16x8*)(ar + 96), bsh[3].v, c4);
            const f32x4 bi = *(const f32x4*)(sb2p + 32 * kt + 8 * g + 4 * h);
            const float e0 = __expf(fminf(c4[0] + bi[0], 60.f));
            const float e1 = __expf(fminf(c4[1] + bi[1], 60.f));
            const float e2 = __expf(fminf(c4[2] + bi[2], 60.f));
            const float e3 = __expf(fminf(c4[3] + bi[3], 60.f));
            psum += (e0 + e1) + (e2 + e3);
            bq.w[2 * h + 0] = pk(e0, e1);
            bq.w[2 * h + 1] = pk(e2, e3);
        }
        const u16* fr = filtn + (size_t)p * 800 + 32 * kt + 8 * g;
        #pragma unroll
        for (int ct = 0; ct < 8; ++ct) {
            const bf16x8 af = *(const bf16x8*)(fr + (size_t)ct * 16 * 800);
            pv[ct] = MFMA(af, bq.v, pv[ct]);
        }
    }
    psum += __shfl_xor(psum, 16);
    psum += __shfl_xor(psum, 32);
    const float inv = 1.f / psum;

    // ---- C-pre: gh via MFMA (deferred; bx kept live instead of bgh) ------
    B8 bgh[4];
    #pragma unroll
    for (int ct = 0; ct < 8; ++ct) {
        const bf16x8 a_g = *(const bf16x8*)(gw1p + (16 * ct + p) * 32 + 8 * g);
        f32x4 cg = (f32x4){0.f, 0.f, 0.f, 0.f};
        cg = MFMA(a_g, bx.v, cg);
        const int cb = 32 * (ct >> 1) + 8 * g + 4 * (ct & 1);
        const f32x4 b2 = *(const f32x4*)(gb1 + cb);
        const f32x4 gg = *(const f32x4*)(glob_gh + n * C_ + cb);
        const float gh0 = fmaxf(cg[0] + b2[0] + gg[0], 0.f), gh1 = fmaxf(cg[1] + b2[1] + gg[1], 0.f);
        const float gh2 = fmaxf(cg[2] + b2[2] + gg[2], 0.f), gh3 = fmaxf(cg[3] + b2[3] + gg[3], 0.f);
        const int m = ct >> 1, o = (ct & 1) * 2;
        bgh[m].w[o] = pk(gh0, gh1); bgh[m].w[o + 1] = pk(gh2, gh3);
    }

    // ---- C: gattn = sigmoid(gw2.gh + gb2); sf = gattn * pv * inv ---------
    B8 bsf[4];
    #pragma unroll
    for (int ct = 0; ct < 8; ++ct) {
        const u16* ar = gw2p + (16 * ct + p) * C_ + 8 * g;
        f32x4 acc = (f32x4){0.f, 0.f, 0.f, 0.f};
        acc = MFMA(*(const bf16x8*)(ar),      bgh[0].v, acc);
        acc = MFMA(*(const bf16x8*)(ar + 32), bgh[1].v, acc);
        acc = MFMA(*(const bf16x8*)(ar + 64), bgh[2].v, acc);
        acc = MFMA(*(const bf16x8*)(ar + 96), bgh[3].v, acc);
        const int cb = 32 * (ct >> 1) + 8 * g + 4 * (ct & 1);
        const f32x4 gb = *(const f32x4*)(gb2 + cb);
        const float s0 = pv[ct][0] * inv / (1.f + __expf(-(acc[0] + gb[0])));
        const float s1 = pv[ct][1] * inv / (1.f + __expf(-(acc[1] + gb[1])));
        const float s2 = pv[ct][2] * inv / (1.f + __expf(-(acc[2] + gb[2])));
        const float s3 = pv[ct][3] * inv / (1.f + __expf(-(acc[3] + gb[3])));
        const int m = ct >> 1, o = (ct & 1) * 2;
        bsf[m].w[o] = pk(s0, s1); bsf[m].w[o + 1] = pk(s2, s3);
    }

    // ---- D: h1 = relu(fw1b.sf + f32 side terms) --------------------------
    float xr[15];
    #pragma unroll
    for (int k = 0; k < 15; ++k) xr[k] = s_x[wid][p][k];
    const int pp = pw + p;
    const float cx = -1.f + 2.f * (float)(pp >> 6) / 63.f;
    const float cy = -1.f + 2.f * (float)(pp & 63) / 63.f;

    B8 bh1[4];
    #pragma unroll
    for (int ct = 0; ct < 8; ++ct) {
        const u16* ar = fw1bp + (16 * ct + p) * C_ + 8 * g;
        f32x4 acc = (f32x4){0.f, 0.f, 0.f, 0.f};
        acc = MFMA(*(const bf16x8*)(ar),      bsf[0].v, acc);
        acc = MFMA(*(const bf16x8*)(ar + 32), bsf[1].v, acc);
        acc = MFMA(*(const bf16x8*)(ar + 64), bsf[2].v, acc);
        acc = MFMA(*(const bf16x8*)(ar + 96), bsf[3].v, acc);
        const int cb = 32 * (ct >> 1) + 8 * g + 4 * (ct & 1);
        f32x4 o4 = *(const f32x4*)(fb1 + cb);
        o4 += *(const f32x4*)(glob_f1 + n * C_ + cb);
        #pragma unroll
        for (int k = 0; k < 15; ++k)
            o4 += xr[k] * *(const f32x4*)(fw1 + k * C_ + cb);
        o4 += cx * *(const f32x4*)(fw1 + 527 * C_ + cb);
        o4 += cy * *(const f32x4*)(fw1 + 528 * C_ + cb);
        const float h0 = fmaxf(acc[0] + o4[0], 0.f), h1v = fmaxf(acc[1] + o4[1], 0.f);
        const float h2 = fmaxf(acc[2] + o4[2], 0.f), h3 = fmaxf(acc[3] + o4[3], 0.f);
        const int m = ct >> 1, o = (ct & 1) * 2;
        bh1[m].w[o] = pk(h0, h1v); bh1[m].w[o + 1] = pk(h2, h3);
    }

    // ---- E: h2 = relu(fw2.h1 + fb2), kept f32 in registers ---------------
    float h2r[8][4];
    #pragma unroll
    for (int ct = 0; ct < 8; ++ct) {
        const u16* ar = fw2p + (16 * ct + p) * C_ + 8 * g;
        f32x4 acc = (f32x4){0.f, 0.f, 0.f, 0.f};
        acc = MFMA(*(const bf16x8*)(ar),      bh1[0].v, acc);
        acc = MFMA(*(const bf16x8*)(ar + 32), bh1[1].v, acc);
        acc = MFMA(*(const bf16x8*)(ar + 64), bh1[2].v, acc);
        acc = MFMA(*(const bf16x8*)(ar + 96), bh1[3].v, acc);
        const int cb = 32 * (ct >> 1) + 8 * g + 4 * (ct & 1);
        const f32x4 o4 = *(const f32x4*)(fb2 + cb);
        #pragma unroll
        for (int r = 0; r < 4; ++r) h2r[ct][r] = fmaxf(acc[r] + o4[r], 0.f);
    }

    // ---- F: deform = h2 @ fw3; reduce across the 4 lane-groups -----------
    float d0 = 0.f, d1 = 0.f, d2 = 0.f;
    #pragma unroll
    for (int ct = 0; ct < 8; ++ct) {
        const int cb = 32 * (ct >> 1) + 8 * g + 4 * (ct & 1);
        #pragma unroll
        for (int r = 0; r < 4; ++r) {
            const float h = h2r[ct][r];
            const float* w3 = fw3 + (cb + r) * 3;
            d0 += h * w3[0]; d1 += h * w3[1]; d2 += h * w3[2];
        }
    }
    d0 += __shfl_xor(d0, 16); d0 += __shfl_xor(d0, 32);
    d1 += __shfl_xor(d1, 16); d1 += __shfl_xor(d1, 32);
    d2 += __shfl_xor(d2, 16); d2 += __shfl_xor(d2, 32);
    if (g == 0) {
        const int gp = n * P_ + pw + p;
        out[gp * 3 + 0] = d0 + fb3[0] + s_x[wid][p][0];
        out[gp * 3 + 1] = d1 + fb3[1] + s_x[wid][p][1];
        out[gp * 3 + 2] = d2 + fb3[2] + s_x[wid][p][2];
    }
}

// ---------------------------------------------------------------------------
// Per-batch normalize in place (f32), 1024 threads.
// ---------------------------------------------------------------------------
__global__ __launch_bounds__(1024) void k_norm(float* __restrict__ out)
{
    __shared__ float red[48];
    __shared__ float red2[16];
    const int n = blockIdx.x, tid = threadIdx.x;
    float* pb = out + (size_t)n * P_ * 3;

    float sx = 0.f, sy = 0.f, sz = 0.f;
    for (int i = tid; i < P_; i += 1024) {
        sx += pb[i * 3 + 0]; sy += pb[i * 3 + 1]; sz += pb[i * 3 + 2];
    }
    #pragma unroll
    for (int m = 32; m >= 1; m >>= 1) {
        sx += __shfl_xor(sx, m); sy += __shfl_xor(sy, m); sz += __shfl_xor(sz, m);
    }
    const int wv = tid >> 6, ln = tid & 63;
    if (ln == 0) { red[wv * 3 + 0] = sx; red[wv * 3 + 1] = sy; red[wv * 3 + 2] = sz; }
    __syncthreads();
    float meanx = 0.f, meany = 0.f, meanz = 0.f;
    #pragma unroll
    for (int w = 0; w < 16; ++w) {
        meanx += red[w * 3 + 0]; meany += red[w * 3 + 1]; meanz += red[w * 3 + 2];
    }
    meanx /= (float)P_; meany /= (float)P_; meanz /= (float)P_;

    float mm = 0.f;
    for (int i = tid; i < P_; i += 1024) {
        const float dx = pb[i * 3 + 0] - meanx;
        const float dy = pb[i * 3 + 1] - meany;
        const float dz = pb[i * 3 + 2] - meanz;
        mm = fmaxf(mm, dx * dx + dy * dy + dz * dz);
    }
    #pragma unroll
    for (int m = 32; m >= 1; m >>= 1) mm = fmaxf(mm, __shfl_xor(mm, m));
    if (ln == 0) red2[wv] = mm;
    __syncthreads();
    mm = 0.f;
    #pragma unroll
    for (int w = 0; w < 16; ++w) mm = fmaxf(mm, red2[w]);
    const float scale = 1.f / (sqrtf(mm) + 1e-8f);

    for (int i = tid; i < P_; i += 1024) {
        pb[i * 3 + 0] = (pb[i * 3 + 0] - meanx) * scale;
        pb[i * 3 + 1] = (pb[i * 3 + 1] - meany) * scale;
        pb[i * 3 + 2] = (pb[i * 3 + 2] - meanz) * scale;
    }
}

// ---------------------------------------------------------------------------
extern "C" void kernel_launch(void* const* d_in, const int* in_sizes, int n_in,
                              void* d_out, int out_size, void* d_ws, size_t ws_size,
                              hipStream_t stream) {
    const float* points    = (const float*)d_in[0];
    const float* transform = (const float*)d_in[1];
    const float* filters   = (const float*)d_in[2];
    const float* enc_glob  = (const float*)d_in[3];
    const float* sw1 = (const float*)d_in[4];
    const float* sb1 = (const float*)d_in[5];
    const float* sw2 = (const float*)d_in[6];
    const float* sb2 = (const float*)d_in[7];
    const float* gw1 = (const float*)d_in[8];
    const float* gb1 = (const float*)d_in[9];
    const float* gw2 = (const float*)d_in[10];
    const float* gb2 = (const float*)d_in[11];
    const float* fw1 = (const float*)d_in[12];
    const float* fb1 = (const float*)d_in[13];
    const float* fw2 = (const float*)d_in[14];
    const float* fb2 = (const float*)d_in[15];
    const float* fw3 = (const float*)d_in[16];
    const float* fb3 = (const float*)d_in[17];

    char* ws = (char*)d_ws;
    u16*   sw2p    = (u16*)(ws + OFF_SW2P);
    u16*   sw1p    = (u16*)(ws + OFF_SW1P);
    u16*   gw1p    = (u16*)(ws + OFF_GW1P);
    u16*   gw2p    = (u16*)(ws + OFF_GW2P);
    u16*   fw1bp   = (u16*)(ws + OFF_FW1BP);
    u16*   fw2p    = (u16*)(ws + OFF_FW2P);
    float* sb2p    = (float*)(ws + OFF_SB2P);
    float* glob_gh = (float*)(ws + OFF_GLOBGH);
    float* glob_f1 = (float*)(ws + OFF_GLOBF1);
    u16*   filtp   = (u16*)(ws + OFF_FILTP);
    float* out     = (float*)d_out;

    k_prep<<<(SG8 + 255) / 256, 256, 0, stream>>>(
        sw1, sw2, sb2, gw1, gw2, fw1, fw2, filters, enc_glob,
        sw2p, sw1p, gw1p, gw2p, fw1bp, fw2p, sb2p, filtp, glob_gh, glob_f1);
    k_mfma<<<N_ * (P_ / 64), 256, 0, stream>>>(
        points, transform, sb1, gb1, gb2, fb1, fb2, fb3, fw1, fw3,
        sw1p, gw1p, sw2p, sb2p, gw2p, fw1bp, fw2p, filtp,
        glob_gh, glob_f1, out);
    k_norm<<<N_, 1024, 0, stream>>>(out);
}

// Round 9
// 239.623 us; speedup vs baseline: 14.5294x; 1.3700x over previous
//
#include <hip/hip_runtime.h>
#include <hip/hip_bf16.h>

#define N_   16
#define P_   4096
#define C_   128
#define HW_  784
#define G_   512

typedef unsigned short u16;
typedef unsigned int   u32;
typedef __attribute__((ext_vector_type(8))) short bf16x8;
typedef __attribute__((ext_vector_type(4))) float f32x4;

union B8 { bf16x8 v; u32 w[4]; };

#define MFMA(a,b,c) __builtin_amdgcn_mfma_f32_16x16x32_bf16((a),(b),(c),0,0,0)

__device__ __forceinline__ u16 f2b(float f) {
    __hip_bfloat16 h = __float2bfloat16(f);
    return *reinterpret_cast<u16*>(&h);
}
__device__ __forceinline__ u32 pk(float lo, float hi) {
    return (u32)f2b(lo) | ((u32)f2b(hi) << 16);
}

// ---------------------------------------------------------------------------
// ws layout (bytes). bf16 A-operand matrices stored with M-dim rows PERMUTED
// so MFMA D-layout (row=4g+reg) lands in B-fragment k-order (k=8g+j):
//   row position (16ct + r) holds true idx 32*(ct>>1) + 8*(r>>2) + 4*(ct&1) + (r&3)
// ---------------------------------------------------------------------------
#define OFF_SW2P    0         // 800x128 bf16 (q rows permuted, q>=784 zero)
#define OFF_SW1P    204800    // 128x32 bf16 (out-c permuted, k>=15 zero)
#define OFF_GW1P    212992    // 128x32 bf16
#define OFF_GW2P    221184    // 128x128 bf16 (out-c permuted)
#define OFF_FW1BP   253952    // 128x128 bf16 (out-c permuted, fw1 rows 529+)
#define OFF_FW2P    286720    // 128x128 bf16 (out-c permuted)
#define OFF_SB2P    319488    // 800 f32 (plain order, q>=784 = -1e30)
#define OFF_GLOBGH  322688    // 16x128 f32 (plain)
#define OFF_GLOBF1  330880    // 16x128 f32 (plain)
#define OFF_FILTP   339072    // 16x128x800 bf16 (c rows permuted, q>=784 zero)

// segment boundaries (flat thread index) for the fused prep kernel
#define SG0 102400    // end sw2p
#define SG1 110592    // end sw1p
#define SG2 118784    // end gw1p
#define SG3 135168    // end gw2p
#define SG4 151552    // end fw1bp
#define SG5 167936    // end fw2p
#define SG6 168736    // end sb2p
#define SG7 1807136   // end filtp
#define SG8 1811232   // end glob precompute

__device__ __forceinline__ int perm_c(int row) {   // row pos -> true index
    const int ct = row >> 4, r = row & 15;
    return 32 * (ct >> 1) + 8 * (r >> 2) + 4 * (ct & 1) + (r & 3);
}

// ---------------------------------------------------------------------------
__global__ __launch_bounds__(256) void k_prep(
    const float* __restrict__ sw1, const float* __restrict__ sw2,
    const float* __restrict__ sb2, const float* __restrict__ gw1,
    const float* __restrict__ gw2, const float* __restrict__ fw1,
    const float* __restrict__ fw2, const float* __restrict__ filters,
    const float* __restrict__ enc_glob,
    u16* __restrict__ sw2p, u16* __restrict__ sw1p, u16* __restrict__ gw1p,
    u16* __restrict__ gw2p, u16* __restrict__ fw1bp, u16* __restrict__ fw2p,
    float* __restrict__ sb2p, u16* __restrict__ filtp,
    float* __restrict__ glob_gh, float* __restrict__ glob_f1)
{
    const int idx = blockIdx.x * 256 + threadIdx.x;
    if (idx < SG0) {                      // sw2p: q-rows permuted per 32-block
        const int r_new = idx >> 7, c = idx & 127;
        const int kt = r_new >> 5, o = r_new & 31, h = (o >> 4) & 1, r = o & 15;
        const int q = kt * 32 + 8 * (r >> 2) + 4 * h + (r & 3);
        sw2p[idx] = (q < HW_) ? f2b(sw2[c * HW_ + q]) : (u16)0;
    } else if (idx < SG1) {               // sw1p
        const int t = idx - SG0;
        const int row = t >> 5, k = t & 31;
        const int c = perm_c(row);
        sw1p[t] = (k < 15) ? f2b(sw1[k * C_ + c]) : (u16)0;
    } else if (idx < SG2) {               // gw1p
        const int t = idx - SG1;
        const int row = t >> 5, k = t & 31;
        const int c = perm_c(row);
        gw1p[t] = (k < 15) ? f2b(gw1[k * C_ + c]) : (u16)0;
    } else if (idx < SG3) {               // gw2p
        const int t = idx - SG2;
        const int row = t >> 7, ci = t & 127;
        gw2p[t] = f2b(gw2[ci * C_ + perm_c(row)]);
    } else if (idx < SG4) {               // fw1bp (fw1 rows 529..656)
        const int t = idx - SG3;
        const int row = t >> 7, ci = t & 127;
        fw1bp[t] = f2b(fw1[(529 + ci) * C_ + perm_c(row)]);
    } else if (idx < SG5) {               // fw2p
        const int t = idx - SG4;
        const int row = t >> 7, ci = t & 127;
        fw2p[t] = f2b(fw2[ci * C_ + perm_c(row)]);
    } else if (idx < SG6) {               // sb2p: plain order + -inf tail
        const int q = idx - SG5;
        sb2p[q] = (q < HW_) ? sb2[q] : -1e30f;
    } else if (idx < SG7) {               // filtp: c-rows permuted, q padded
        const int t = idx - SG6;
        const int nn = t / 102400;
        const int rr = t % 102400;
        const int row = rr / 800, q = rr % 800;
        const int c = perm_c(row);
        filtp[t] = (q < HW_) ? f2b(filters[((size_t)nn * C_ + c) * HW_ + q]) : (u16)0;
    } else if (idx < SG8) {               // glob_gh / glob_f1 (plain layout)
        const int t = idx - SG7;
        const int which = t >> 11;
        const int nn = (t >> 7) & 15, c = t & 127;
        const float* W = which ? fw1 : gw1;
        const float* gv = enc_glob + nn * G_;
        float acc = 0.f;
        for (int k = 0; k < G_; ++k)
            acc += gv[k] * W[(15 + k) * C_ + c];
        (which ? glob_f1 : glob_gh)[nn * C_ + c] = acc;
    }
}

// ---------------------------------------------------------------------------
// Main kernel: 128 points/block, 4 waves, 32 points/wave (two B-fragments
// f=0,1 per MFMA A-load: halves weight traffic, doubles per-load ILP).
// All 16 frag loads of a kt iteration are issued up-front so they cluster
// into one latency bubble instead of 16 serial ones (round-8 diagnosis).
// ---------------------------------------------------------------------------
__global__ __launch_bounds__(256) void k_mfma(
    const float* __restrict__ points, const float* __restrict__ transform,
    const float* __restrict__ sb1, const float* __restrict__ gb1,
    const float* __restrict__ gb2, const float* __restrict__ fb1,
    const float* __restrict__ fb2, const float* __restrict__ fb3,
    const float* __restrict__ fw1, const float* __restrict__ fw3,
    const u16* __restrict__ sw1p, const u16* __restrict__ gw1p,
    const u16* __restrict__ sw2p, const float* __restrict__ sb2p,
    const u16* __restrict__ gw2p, const u16* __restrict__ fw1bp,
    const u16* __restrict__ fw2p, const u16* __restrict__ filtp,
    const float* __restrict__ glob_gh, const float* __restrict__ glob_f1,
    float* __restrict__ out)
{
    __shared__ __align__(16) float s_x[4][32][16];

    const int tid = threadIdx.x, wid = tid >> 6, lane = tid & 63;
    const int p = lane & 15, g = lane >> 4;
    // XCD swizzle: 512 blocks, 64-chunk per XCD -> 2 distinct n per XCD L2.
    const int bid = blockIdx.x;
    const int nb  = (bid & 7) * 64 + (bid >> 3);
    const int n   = nb >> 5;
    const int pw  = ((nb & 31) << 7) + (wid << 5);

    // ---- A1: inputs to LDS (per-wave, 32 points) -------------------------
    for (int i = lane; i < 512; i += 64) {
        const int pt = i >> 4, k = i & 15;
        const int gp = n * P_ + pw + pt;
        float v = 0.f;
        if (k < 3)       v = points[gp * 3 + k];
        else if (k < 15) v = transform[gp * 12 + k - 3];
        s_x[wid][pt][k] = v;
    }
    asm volatile("s_waitcnt lgkmcnt(0)" ::: "memory");
    __builtin_amdgcn_sched_barrier(0);

    // ---- x as B-fragments (k = 8g+j; k>=15 hits zero A rows) -------------
    B8 bx[2];
    #pragma unroll
    for (int f = 0; f < 2; ++f) {
        bx[f].w[0] = bx[f].w[1] = bx[f].w[2] = bx[f].w[3] = 0u;
        if (g < 2) {
            const float* xs = &s_x[wid][p + 16 * f][8 * g];
            bx[f].w[0] = pk(xs[0], xs[1]); bx[f].w[1] = pk(xs[2], xs[3]);
            bx[f].w[2] = pk(xs[4], xs[5]); bx[f].w[3] = pk(xs[6], xs[7]);
        }
    }

    // ---- A2: sh via MFMA (output lands directly in B-frag order) ---------
    B8 bsh[4][2];
    #pragma unroll
    for (int ct = 0; ct < 8; ++ct) {
        const bf16x8 a_s = *(const bf16x8*)(sw1p + (16 * ct + p) * 32 + 8 * g);
        const int cb = 32 * (ct >> 1) + 8 * g + 4 * (ct & 1);
        const f32x4 b1 = *(const f32x4*)(sb1 + cb);
        const int m = ct >> 1, o = (ct & 1) * 2;
        #pragma unroll
        for (int f = 0; f < 2; ++f) {
            f32x4 cs = (f32x4){0.f, 0.f, 0.f, 0.f};
            cs = MFMA(a_s, bx[f].v, cs);
            const float s0 = fmaxf(cs[0] + b1[0], 0.f), s1 = fmaxf(cs[1] + b1[1], 0.f);
            const float s2 = fmaxf(cs[2] + b1[2], 0.f), s3 = fmaxf(cs[3] + b1[3], 0.f);
            bsh[m][f].w[o] = pk(s0, s1); bsh[m][f].w[o + 1] = pk(s2, s3);
        }
    }

    // ---- B: logits -> exp -> fused PV ------------------------------------
    f32x4 pv[8][2];
    #pragma unroll
    for (int ct = 0; ct < 8; ++ct)
        #pragma unroll
        for (int f = 0; f < 2; ++f) pv[ct][f] = (f32x4){0.f, 0.f, 0.f, 0.f};
    float psum0 = 0.f, psum1 = 0.f;
    const u16* filtn = filtp + (size_t)n * (C_ * 800);

    for (int kt = 0; kt < 25; ++kt) {
        // -- issue ALL 16 frag loads up-front (one clustered bubble) --
        const u16* ar0 = sw2p + (size_t)(32 * kt + p) * C_ + 8 * g;
        const u16* ar1 = ar0 + 16 * C_;
        const u16* fr  = filtn + (size_t)p * 800 + 32 * kt + 8 * g;
        B8 aw[8], af[8];
        #pragma unroll
        for (int kk = 0; kk < 4; ++kk) {
            aw[kk].v     = *(const bf16x8*)(ar0 + 32 * kk);
            aw[4 + kk].v = *(const bf16x8*)(ar1 + 32 * kk);
        }
        #pragma unroll
        for (int ct = 0; ct < 8; ++ct)
            af[ct].v = *(const bf16x8*)(fr + (size_t)ct * 16 * 800);

        // -- logits + exp for both point-fragments --
        B8 bq[2];
        #pragma unroll
        for (int h = 0; h < 2; ++h) {
            const f32x4 bi = *(const f32x4*)(sb2p + 32 * kt + 8 * g + 4 * h);
            #pragma unroll
            for (int f = 0; f < 2; ++f) {
                f32x4 c4 = (f32x4){0.f, 0.f, 0.f, 0.f};
                c4 = MFMA(aw[4 * h + 0].v, bsh[0][f].v, c4);
                c4 = MFMA(aw[4 * h + 1].v, bsh[1][f].v, c4);
                c4 = MFMA(aw[4 * h + 2].v, bsh[2][f].v, c4);
                c4 = MFMA(aw[4 * h + 3].v, bsh[3][f].v, c4);
                const float e0 = __expf(fminf(c4[0] + bi[0], 60.f));
                const float e1 = __expf(fminf(c4[1] + bi[1], 60.f));
                const float e2 = __expf(fminf(c4[2] + bi[2], 60.f));
                const float e3 = __expf(fminf(c4[3] + bi[3], 60.f));
                if (f == 0) psum0 += (e0 + e1) + (e2 + e3);
                else        psum1 += (e0 + e1) + (e2 + e3);
                bq[f].w[2 * h + 0] = pk(e0, e1);
                bq[f].w[2 * h + 1] = pk(e2, e3);
            }
        }
        // -- PV accumulate --
        #pragma unroll
        for (int ct = 0; ct < 8; ++ct) {
            pv[ct][0] = MFMA(af[ct].v, bq[0].v, pv[ct][0]);
            pv[ct][1] = MFMA(af[ct].v, bq[1].v, pv[ct][1]);
        }
    }
    psum0 += __shfl_xor(psum0, 16); psum0 += __shfl_xor(psum0, 32);
    psum1 += __shfl_xor(psum1, 16); psum1 += __shfl_xor(psum1, 32);
    const float inv0 = 1.f / psum0, inv1 = 1.f / psum1;

    // ---- C-pre: gh via MFMA (deferred: bx is 8 regs vs bgh's 32) ---------
    B8 bgh[4][2];
    #pragma unroll
    for (int ct = 0; ct < 8; ++ct) {
        const bf16x8 a_g = *(const bf16x8*)(gw1p + (16 * ct + p) * 32 + 8 * g);
        const int cb = 32 * (ct >> 1) + 8 * g + 4 * (ct & 1);
        const f32x4 b2 = *(const f32x4*)(gb1 + cb);
        const f32x4 gg = *(const f32x4*)(glob_gh + n * C_ + cb);
        const int m = ct >> 1, o = (ct & 1) * 2;
        #pragma unroll
        for (int f = 0; f < 2; ++f) {
            f32x4 cg = (f32x4){0.f, 0.f, 0.f, 0.f};
            cg = MFMA(a_g, bx[f].v, cg);
            const float g0 = fmaxf(cg[0] + b2[0] + gg[0], 0.f), g1 = fmaxf(cg[1] + b2[1] + gg[1], 0.f);
            const float g2 = fmaxf(cg[2] + b2[2] + gg[2], 0.f), g3 = fmaxf(cg[3] + b2[3] + gg[3], 0.f);
            bgh[m][f].w[o] = pk(g0, g1); bgh[m][f].w[o + 1] = pk(g2, g3);
        }
    }

    // ---- C: gattn = sigmoid(gw2.gh + gb2); sf = gattn * pv * inv ---------
    B8 bsf[4][2];
    #pragma unroll
    for (int ct = 0; ct < 8; ++ct) {
        const u16* ar = gw2p + (16 * ct + p) * C_ + 8 * g;
        const bf16x8 a0 = *(const bf16x8*)(ar),      a1 = *(const bf16x8*)(ar + 32);
        const bf16x8 a2 = *(const bf16x8*)(ar + 64), a3 = *(const bf16x8*)(ar + 96);
        const int cb = 32 * (ct >> 1) + 8 * g + 4 * (ct & 1);
        const f32x4 gb = *(const f32x4*)(gb2 + cb);
        const int m = ct >> 1, o = (ct & 1) * 2;
        #pragma unroll
        for (int f = 0; f < 2; ++f) {
            f32x4 acc = (f32x4){0.f, 0.f, 0.f, 0.f};
            acc = MFMA(a0, bgh[0][f].v, acc);
            acc = MFMA(a1, bgh[1][f].v, acc);
            acc = MFMA(a2, bgh[2][f].v, acc);
            acc = MFMA(a3, bgh[3][f].v, acc);
            const float iv = f ? inv1 : inv0;
            const float s0 = pv[ct][f][0] * iv / (1.f + __expf(-(acc[0] + gb[0])));
            const float s1 = pv[ct][f][1] * iv / (1.f + __expf(-(acc[1] + gb[1])));
            const float s2 = pv[ct][f][2] * iv / (1.f + __expf(-(acc[2] + gb[2])));
            const float s3 = pv[ct][f][3] * iv / (1.f + __expf(-(acc[3] + gb[3])));
            bsf[m][f].w[o] = pk(s0, s1); bsf[m][f].w[o + 1] = pk(s2, s3);
        }
    }

    // ---- D: h1 = relu(fw1b.sf + f32 side terms) --------------------------
    float xr[2][15];
    #pragma unroll
    for (int f = 0; f < 2; ++f)
        #pragma unroll
        for (int k = 0; k < 15; ++k) xr[f][k] = s_x[wid][p + 16 * f][k];
    float cxv[2], cyv[2];
    #pragma unroll
    for (int f = 0; f < 2; ++f) {
        const int pp = pw + p + 16 * f;
        cxv[f] = -1.f + 2.f * (float)(pp >> 6) / 63.f;
        cyv[f] = -1.f + 2.f * (float)(pp & 63) / 63.f;
    }

    B8 bh1[4][2];
    #pragma unroll
    for (int ct = 0; ct < 8; ++ct) {
        const u16* ar = fw1bp + (16 * ct + p) * C_ + 8 * g;
        const bf16x8 a0 = *(const bf16x8*)(ar),      a1 = *(const bf16x8*)(ar + 32);
        const bf16x8 a2 = *(const bf16x8*)(ar + 64), a3 = *(const bf16x8*)(ar + 96);
        const int cb = 32 * (ct >> 1) + 8 * g + 4 * (ct & 1);
        const f32x4 fb = *(const f32x4*)(fb1 + cb);
        const f32x4 gf = *(const f32x4*)(glob_f1 + n * C_ + cb);
        const int m = ct >> 1, o = (ct & 1) * 2;
        #pragma unroll
        for (int f = 0; f < 2; ++f) {
            f32x4 acc = (f32x4){0.f, 0.f, 0.f, 0.f};
            acc = MFMA(a0, bsf[0][f].v, acc);
            acc = MFMA(a1, bsf[1][f].v, acc);
            acc = MFMA(a2, bsf[2][f].v, acc);
            acc = MFMA(a3, bsf[3][f].v, acc);
            f32x4 o4 = fb + gf;
            #pragma unroll
            for (int k = 0; k < 15; ++k)
                o4 += xr[f][k] * *(const f32x4*)(fw1 + k * C_ + cb);
            o4 += cxv[f] * *(const f32x4*)(fw1 + 527 * C_ + cb);
            o4 += cyv[f] * *(const f32x4*)(fw1 + 528 * C_ + cb);
            const float h0 = fmaxf(acc[0] + o4[0], 0.f), h1v = fmaxf(acc[1] + o4[1], 0.f);
            const float h2 = fmaxf(acc[2] + o4[2], 0.f), h3 = fmaxf(acc[3] + o4[3], 0.f);
            bh1[m][f].w[o] = pk(h0, h1v); bh1[m][f].w[o + 1] = pk(h2, h3);
        }
    }

    // ---- E: h2 = relu(fw2.h1 + fb2), f32 in registers --------------------
    float h2r[8][2][4];
    #pragma unroll
    for (int ct = 0; ct < 8; ++ct) {
        const u16* ar = fw2p + (16 * ct + p) * C_ + 8 * g;
        const bf16x8 a0 = *(const bf16x8*)(ar),      a1 = *(const bf16x8*)(ar + 32);
        const bf16x8 a2 = *(const bf16x8*)(ar + 64), a3 = *(const bf16x8*)(ar + 96);
        const int cb = 32 * (ct >> 1) + 8 * g + 4 * (ct & 1);
        const f32x4 o4 = *(const f32x4*)(fb2 + cb);
        #pragma unroll
        for (int f = 0; f < 2; ++f) {
            f32x4 acc = (f32x4){0.f, 0.f, 0.f, 0.f};
            acc = MFMA(a0, bh1[0][f].v, acc);
            acc = MFMA(a1, bh1[1][f].v, acc);
            acc = MFMA(a2, bh1[2][f].v, acc);
            acc = MFMA(a3, bh1[3][f].v, acc);
            #pragma unroll
            for (int r = 0; r < 4; ++r) h2r[ct][f][r] = fmaxf(acc[r] + o4[r], 0.f);
        }
    }

    // ---- F: deform = h2 @ fw3; reduce across the 4 lane-groups -----------
    #pragma unroll
    for (int f = 0; f < 2; ++f) {
        float d0 = 0.f, d1 = 0.f, d2 = 0.f;
        #pragma unroll
        for (int ct = 0; ct < 8; ++ct) {
            const int cb = 32 * (ct >> 1) + 8 * g + 4 * (ct & 1);
            #pragma unroll
            for (int r = 0; r < 4; ++r) {
                const float h = h2r[ct][f][r];
                const float* w3 = fw3 + (cb + r) * 3;
                d0 += h * w3[0]; d1 += h * w3[1]; d2 += h * w3[2];
            }
        }
        d0 += __shfl_xor(d0, 16); d0 += __shfl_xor(d0, 32);
        d1 += __shfl_xor(d1, 16); d1 += __shfl_xor(d1, 32);
        d2 += __shfl_xor(d2, 16); d2 += __shfl_xor(d2, 32);
        if (g == 0) {
            const int pt = p + 16 * f;
            const int gp = n * P_ + pw + pt;
            out[gp * 3 + 0] = d0 + fb3[0] + s_x[wid][pt][0];
            out[gp * 3 + 1] = d1 + fb3[1] + s_x[wid][pt][1];
            out[gp * 3 + 2] = d2 + fb3[2] + s_x[wid][pt][2];
        }
    }
}

// ---------------------------------------------------------------------------
// Per-batch normalize in place (f32), 1024 threads.
// ---------------------------------------------------------------------------
__global__ __launch_bounds__(1024) void k_norm(float* __restrict__ out)
{
    __shared__ float red[48];
    __shared__ float red2[16];
    const int n = blockIdx.x, tid = threadIdx.x;
    float* pb = out + (size_t)n * P_ * 3;

    float sx = 0.f, sy = 0.f, sz = 0.f;
    for (int i = tid; i < P_; i += 1024) {
        sx += pb[i * 3 + 0]; sy += pb[i * 3 + 1]; sz += pb[i * 3 + 2];
    }
    #pragma unroll
    for (int m = 32; m >= 1; m >>= 1) {
        sx += __shfl_xor(sx, m); sy += __shfl_xor(sy, m); sz += __shfl_xor(sz, m);
    }
    const int wv = tid >> 6, ln = tid & 63;
    if (ln == 0) { red[wv * 3 + 0] = sx; red[wv * 3 + 1] = sy; red[wv * 3 + 2] = sz; }
    __syncthreads();
    float meanx = 0.f, meany = 0.f, meanz = 0.f;
    #pragma unroll
    for (int w = 0; w < 16; ++w) {
        meanx += red[w * 3 + 0]; meany += red[w * 3 + 1]; meanz += red[w * 3 + 2];
    }
    meanx /= (float)P_; meany /= (float)P_; meanz /= (float)P_;

    float mm = 0.f;
    for (int i = tid; i < P_; i += 1024) {
        const float dx = pb[i * 3 + 0] - meanx;
        const float dy = pb[i * 3 + 1] - meany;
        const float dz = pb[i * 3 + 2] - meanz;
        mm = fmaxf(mm, dx * dx + dy * dy + dz * dz);
    }
    #pragma unroll
    for (int m = 32; m >= 1; m >>= 1) mm = fmaxf(mm, __shfl_xor(mm, m));
    if (ln == 0) red2[wv] = mm;
    __syncthreads();
    mm = 0.f;
    #pragma unroll
    for (int w = 0; w < 16; ++w) mm = fmaxf(mm, red2[w]);
    const float scale = 1.f / (sqrtf(mm) + 1e-8f);

    for (int i = tid; i < P_; i += 1024) {
        pb[i * 3 + 0] = (pb[i * 3 + 0] - meanx) * scale;
        pb[i * 3 + 1] = (pb[i * 3 + 1] - meany) * scale;
        pb[i * 3 + 2] = (pb[i * 3 + 2] - meanz) * scale;
    }
}

// ---------------------------------------------------------------------------
extern "C" void kernel_launch(void* const* d_in, const int* in_sizes, int n_in,
                              void* d_out, int out_size, void* d_ws, size_t ws_size,
                              hipStream_t stream) {
    const float* points    = (const float*)d_in[0];
    const float* transform = (const float*)d_in[1];
    const float* filters   = (const float*)d_in[2];
    const float* enc_glob  = (const float*)d_in[3];
    const float* sw1 = (const float*)d_in[4];
    const float* sb1 = (const float*)d_in[5];
    const float* sw2 = (const float*)d_in[6];
    const float* sb2 = (const float*)d_in[7];
    const float* gw1 = (const float*)d_in[8];
    const float* gb1 = (const float*)d_in[9];
    const float* gw2 = (const float*)d_in[10];
    const float* gb2 = (const float*)d_in[11];
    const float* fw1 = (const float*)d_in[12];
    const float* fb1 = (const float*)d_in[13];
    const float* fw2 = (const float*)d_in[14];
    const float* fb2 = (const float*)d_in[15];
    const float* fw3 = (const float*)d_in[16];
    const float* fb3 = (const float*)d_in[17];

    char* ws = (char*)d_ws;
    u16*   sw2p    = (u16*)(ws + OFF_SW2P);
    u16*   sw1p    = (u16*)(ws + OFF_SW1P);
    u16*   gw1p    = (u16*)(ws + OFF_GW1P);
    u16*   gw2p    = (u16*)(ws + OFF_GW2P);
    u16*   fw1bp   = (u16*)(ws + OFF_FW1BP);
    u16*   fw2p    = (u16*)(ws + OFF_FW2P);
    float* sb2p    = (float*)(ws + OFF_SB2P);
    float* glob_gh = (float*)(ws + OFF_GLOBGH);
    float* glob_f1 = (float*)(ws + OFF_GLOBF1);
    u16*   filtp   = (u16*)(ws + OFF_FILTP);
    float* out     = (float*)d_out;

    k_prep<<<(SG8 + 255) / 256, 256, 0, stream>>>(
        sw1, sw2, sb2, gw1, gw2, fw1, fw2, filters, enc_glob,
        sw2p, sw1p, gw1p, gw2p, fw1bp, fw2p, sb2p, filtp, glob_gh, glob_f1);
    k_mfma<<<N_ * (P_ / 128), 256, 0, stream>>>(
        points, transform, sb1, gb1, gb2, fb1, fb2, fb3, fw1, fw3,
        sw1p, gw1p, sw2p, sb2p, gw2p, fw1bp, fw2p, filtp,
        glob_gh, glob_f1, out);
    k_norm<<<N_, 1024, 0, stream>>>(out);
}

// Round 10
// 211.521 us; speedup vs baseline: 16.4598x; 1.1329x over previous
//
#include <hip/hip_runtime.h>
#include <hip/hip_bf16.h>

#define N_   16
#define P_   4096
#define C_   128
#define HW_  784
#define G_   512

typedef unsigned short u16;
typedef unsigned int   u32;
typedef __attribute__((ext_vector_type(8))) short bf16x8;
typedef __attribute__((ext_vector_type(4))) float f32x4;

union B8 { bf16x8 v; u32 w[4]; };

#define MFMA(a,b,c) __builtin_amdgcn_mfma_f32_16x16x32_bf16((a),(b),(c),0,0,0)

__device__ __forceinline__ u16 f2b(float f) {
    __hip_bfloat16 h = __float2bfloat16(f);
    return *reinterpret_cast<u16*>(&h);
}
__device__ __forceinline__ u32 pk(float lo, float hi) {
    return (u32)f2b(lo) | ((u32)f2b(hi) << 16);
}

// ---------------------------------------------------------------------------
// ws layout (bytes). bf16 A-operand matrices stored with M-dim rows PERMUTED
// so MFMA D-layout (row=4g+reg) lands in B-fragment k-order (k=8g+j):
//   row position (16ct + r) holds true idx 32*(ct>>1) + 8*(r>>2) + 4*(ct&1) + (r&3)
// filt is NOT prepped any more: k_mfma stages f32 filters -> bf16 LDS per
// 32-q chunk (double-buffered).
// ---------------------------------------------------------------------------
#define OFF_SW2P    0         // 800x128 bf16 (q rows permuted, q>=784 zero)
#define OFF_SW1P    204800    // 128x32 bf16 (out-c permuted, k>=15 zero)
#define OFF_GW1P    212992    // 128x32 bf16
#define OFF_GW2P    221184    // 128x128 bf16 (out-c permuted)
#define OFF_FW1BP   253952    // 128x128 bf16 (out-c permuted, fw1 rows 529+)
#define OFF_FW2P    286720    // 128x128 bf16 (out-c permuted)
#define OFF_SB2P    319488    // 800 f32 (plain order, q>=784 = -1e30)
#define OFF_GLOBGH  322688    // 16x128 f32
#define OFF_GLOBF1  330880    // 16x128 f32
#define OFF_FW1SP   339072    // 128x32 bf16 (perm rows; k<15 fw1[k], 15->row527, 16->row528, else 0)
#define OFF_FW3P    347264    // 128x4 f32 (perm rows of fw3, 4th = 0)

// prep segment ends (flat thread index)
#define E0 102400   // sw2p  800*128
#define E1 110592   // sw1p  128*32
#define E2 118784   // gw1p  128*32
#define E3 135168   // gw2p  128*128
#define E4 151552   // fw1bp 128*128
#define E5 167936   // fw2p  128*128
#define E6 168736   // sb2p  800
#define E7 185120   // glob  2*16*128*4 (4-way k-split)
#define E8 189216   // fw1sp 128*32
#define E9 189728   // fw3p  128*4

__device__ __forceinline__ int perm_c(int row) {   // row pos -> true index
    const int ct = row >> 4, r = row & 15;
    return 32 * (ct >> 1) + 8 * (r >> 2) + 4 * (ct & 1) + (r & 3);
}

// ---------------------------------------------------------------------------
__global__ __launch_bounds__(256) void k_prep(
    const float* __restrict__ sw1, const float* __restrict__ sw2,
    const float* __restrict__ sb2, const float* __restrict__ gw1,
    const float* __restrict__ gw2, const float* __restrict__ fw1,
    const float* __restrict__ fw2, const float* __restrict__ fw3,
    const float* __restrict__ enc_glob,
    u16* __restrict__ sw2p, u16* __restrict__ sw1p, u16* __restrict__ gw1p,
    u16* __restrict__ gw2p, u16* __restrict__ fw1bp, u16* __restrict__ fw2p,
    float* __restrict__ sb2p, u16* __restrict__ fw1sp, float* __restrict__ fw3p,
    float* __restrict__ glob_gh, float* __restrict__ glob_f1)
{
    const int idx = blockIdx.x * 256 + threadIdx.x;
    if (idx < E0) {                       // sw2p: q-rows permuted per 32-block
        const int r_new = idx >> 7, c = idx & 127;
        const int kt = r_new >> 5, o = r_new & 31, h = (o >> 4) & 1, r = o & 15;
        const int q = kt * 32 + 8 * (r >> 2) + 4 * h + (r & 3);
        sw2p[idx] = (q < HW_) ? f2b(sw2[c * HW_ + q]) : (u16)0;
    } else if (idx < E1) {                // sw1p
        const int t = idx - E0;
        const int row = t >> 5, k = t & 31;
        const int c = perm_c(row);
        sw1p[t] = (k < 15) ? f2b(sw1[k * C_ + c]) : (u16)0;
    } else if (idx < E2) {                // gw1p
        const int t = idx - E1;
        const int row = t >> 5, k = t & 31;
        const int c = perm_c(row);
        gw1p[t] = (k < 15) ? f2b(gw1[k * C_ + c]) : (u16)0;
    } else if (idx < E3) {                // gw2p
        const int t = idx - E2;
        const int row = t >> 7, ci = t & 127;
        gw2p[t] = f2b(gw2[ci * C_ + perm_c(row)]);
    } else if (idx < E4) {                // fw1bp (fw1 rows 529..656)
        const int t = idx - E3;
        const int row = t >> 7, ci = t & 127;
        fw1bp[t] = f2b(fw1[(529 + ci) * C_ + perm_c(row)]);
    } else if (idx < E5) {                // fw2p
        const int t = idx - E4;
        const int row = t >> 7, ci = t & 127;
        fw2p[t] = f2b(fw2[ci * C_ + perm_c(row)]);
    } else if (idx < E6) {                // sb2p: plain order + -inf tail
        const int q = idx - E5;
        sb2p[q] = (q < HW_) ? sb2[q] : -1e30f;
    } else if (idx < E7) {                // glob: 4 threads per output, k-split
        const int t = idx - E6;           // 0..16383
        const int sub = t & 3, r = t >> 2;
        const int which = r >> 11, nn = (r >> 7) & 15, c = r & 127;
        const float* W = which ? fw1 : gw1;
        const float* gv = enc_glob + nn * G_ + sub * 128;
        const float* Wp = W + (15 + sub * 128) * C_ + c;
        float acc = 0.f;
        for (int k = 0; k < 128; ++k) acc += gv[k] * Wp[k * C_];
        acc += __shfl_xor(acc, 1);
        acc += __shfl_xor(acc, 2);
        if (sub == 0) (which ? glob_f1 : glob_gh)[nn * C_ + c] = acc;
    } else if (idx < E8) {                // fw1sp: x/coord side-weights
        const int t = idx - E7;
        const int row = t >> 5, k = t & 31;
        const int c = perm_c(row);
        float v = 0.f;
        if (k < 15)       v = fw1[k * C_ + c];
        else if (k == 15) v = fw1[527 * C_ + c];
        else if (k == 16) v = fw1[528 * C_ + c];
        fw1sp[t] = f2b(v);
    } else if (idx < E9) {                // fw3p: perm rows of fw3, padded
        const int t = idx - E8;
        const int row = t >> 2, j = t & 3;
        fw3p[t] = (j < 3) ? fw3[perm_c(row) * 3 + j] : 0.f;
    }
}

// ---------------------------------------------------------------------------
// Main kernel: 128 points/block, 4 waves, 32 points/wave.
// kt loop: LDS double-buffered chunks of sw2p (32x128 bf16) and filters
// (128x32, staged f32->bf16 on the fly), cooperatively staged ONCE per block
// (kills the 4x per-wave L2 redundancy). T14 split: global loads issued at
// top of body, ds_write + __syncthreads at bottom -> HBM/L2 latency hides
// under the MFMA+exp compute of the current chunk.
// ---------------------------------------------------------------------------
__global__ __launch_bounds__(256) void k_mfma(
    const float* __restrict__ points, const float* __restrict__ transform,
    const float* __restrict__ filters,
    const float* __restrict__ sb1, const float* __restrict__ gb1,
    const float* __restrict__ gb2, const float* __restrict__ fb1,
    const float* __restrict__ fb2, const float* __restrict__ fb3,
    const u16* __restrict__ sw1p, const u16* __restrict__ gw1p,
    const u16* __restrict__ sw2p, const float* __restrict__ sb2p,
    const u16* __restrict__ gw2p, const u16* __restrict__ fw1bp,
    const u16* __restrict__ fw2p, const u16* __restrict__ fw1sp,
    const float* __restrict__ fw3p,
    const float* __restrict__ glob_gh, const float* __restrict__ glob_f1,
    float* __restrict__ out)
{
    __shared__ __align__(16) float s_x[4][32][16];   // 8 KB
    __shared__ __align__(16) u16 s_w[2][32][136];    // 17408 B (pad 136: ds_read 2-way)
    __shared__ __align__(16) u16 s_f[2][128][36];    // 18432 B (pad 36)

    const int tid = threadIdx.x, wid = tid >> 6, lane = tid & 63;
    const int p = lane & 15, g = lane >> 4;
    // XCD swizzle: 512 blocks, 64-chunk per XCD -> 2 distinct n per XCD L2.
    const int bid = blockIdx.x;
    const int nb  = (bid & 7) * 64 + (bid >> 3);
    const int n   = nb >> 5;
    const int pw  = ((nb & 31) << 7) + (wid << 5);

    const float* filtn = filters + (size_t)n * C_ * HW_;
    // staging slot coords (fixed per thread)
    const int swrow = tid >> 4, swc = tid & 15;   // sw2p: rows swrow/+16, 16B col swc
    const int frp   = tid >> 2, fc16 = tid & 3;   // filt: rows frp/+64, 16B col fc16
    const int fct0  = perm_c(frp);                // true filter row (row frp)
                                                  // row frp+64 -> fct0 + 64

    // ---- A1: inputs to LDS (per-wave, 32 points) -------------------------
    for (int i = lane; i < 512; i += 64) {
        const int pt = i >> 4, k = i & 15;
        const int gp = n * P_ + pw + pt;
        float v = 0.f;
        if (k < 3)       v = points[gp * 3 + k];
        else if (k < 15) v = transform[gp * 12 + k - 3];
        s_x[wid][pt][k] = v;
    }

    // ---- stage chunk kt=0 into buffer 0 ----------------------------------
    {
        const bf16x8 w0 = *(const bf16x8*)(sw2p + (size_t)swrow * C_ + swc * 8);
        const bf16x8 w1 = *(const bf16x8*)(sw2p + (size_t)(16 + swrow) * C_ + swc * 8);
        const float* fb_ = filtn + (size_t)fct0 * HW_ + fc16 * 8;
        const f32x4 f00 = *(const f32x4*)(fb_);
        const f32x4 f01 = *(const f32x4*)(fb_ + 4);
        const f32x4 f10 = *(const f32x4*)(fb_ + (size_t)64 * HW_);
        const f32x4 f11 = *(const f32x4*)(fb_ + (size_t)64 * HW_ + 4);
        *(bf16x8*)&s_w[0][swrow][swc * 8]      = w0;
        *(bf16x8*)&s_w[0][16 + swrow][swc * 8] = w1;
        B8 pf;
        pf.w[0] = pk(f00[0], f00[1]); pf.w[1] = pk(f00[2], f00[3]);
        pf.w[2] = pk(f01[0], f01[1]); pf.w[3] = pk(f01[2], f01[3]);
        *(bf16x8*)&s_f[0][frp][fc16 * 8] = pf.v;
        pf.w[0] = pk(f10[0], f10[1]); pf.w[1] = pk(f10[2], f10[3]);
        pf.w[2] = pk(f11[0], f11[1]); pf.w[3] = pk(f11[2], f11[3]);
        *(bf16x8*)&s_f[0][64 + frp][fc16 * 8] = pf.v;
    }
    __syncthreads();

    // ---- bxc: [x(15), cx, cy, 0...] as B-fragment (k = 8g+j) -------------
    // Shared by sh/gh (k>=15 weight rows are zero) and the D side-term.
    B8 bxc[2];
    #pragma unroll
    for (int f = 0; f < 2; ++f) {
        bxc[f].w[0] = bxc[f].w[1] = bxc[f].w[2] = bxc[f].w[3] = 0u;
        const float* xs = &s_x[wid][p + 16 * f][0];
        const int pp = pw + p + 16 * f;
        const float cx = -1.f + 2.f * (float)(pp >> 6) / 63.f;
        const float cy = -1.f + 2.f * (float)(pp & 63) / 63.f;
        if (g == 0) {
            bxc[f].w[0] = pk(xs[0], xs[1]);  bxc[f].w[1] = pk(xs[2], xs[3]);
            bxc[f].w[2] = pk(xs[4], xs[5]);  bxc[f].w[3] = pk(xs[6], xs[7]);
        } else if (g == 1) {
            bxc[f].w[0] = pk(xs[8], xs[9]);  bxc[f].w[1] = pk(xs[10], xs[11]);
            bxc[f].w[2] = pk(xs[12], xs[13]); bxc[f].w[3] = pk(xs[14], cx);
        } else if (g == 2) {
            bxc[f].w[0] = pk(cy, 0.f);
        }
    }

    // ---- A2: sh via MFMA -------------------------------------------------
    B8 bsh[4][2];
    #pragma unroll
    for (int ct = 0; ct < 8; ++ct) {
        const bf16x8 a_s = *(const bf16x8*)(sw1p + (16 * ct + p) * 32 + 8 * g);
        const int cb = 32 * (ct >> 1) + 8 * g + 4 * (ct & 1);
        const f32x4 b1 = *(const f32x4*)(sb1 + cb);
        const int m = ct >> 1, o = (ct & 1) * 2;
        #pragma unroll
        for (int f = 0; f < 2; ++f) {
            f32x4 cs = (f32x4){0.f, 0.f, 0.f, 0.f};
            cs = MFMA(a_s, bxc[f].v, cs);
            const float s0 = fmaxf(cs[0] + b1[0], 0.f), s1 = fmaxf(cs[1] + b1[1], 0.f);
            const float s2 = fmaxf(cs[2] + b1[2], 0.f), s3 = fmaxf(cs[3] + b1[3], 0.f);
            bsh[m][f].w[o] = pk(s0, s1); bsh[m][f].w[o + 1] = pk(s2, s3);
        }
    }

    // ---- B: kt loop, double-buffered LDS ---------------------------------
    f32x4 pv[8][2];
    #pragma unroll
    for (int ct = 0; ct < 8; ++ct)
        #pragma unroll
        for (int f = 0; f < 2; ++f) pv[ct][f] = (f32x4){0.f, 0.f, 0.f, 0.f};
    float psum0 = 0.f, psum1 = 0.f;

    for (int kt = 0; kt < 25; ++kt) {
        const int cur = kt & 1, nxt = cur ^ 1;
        // -- T14: issue next chunk's global loads first --
        bf16x8 stw0, stw1;
        f32x4 sf00, sf01, sf10, sf11;
        if (kt < 24) {
            const int q0 = 32 * (kt + 1);
            stw0 = *(const bf16x8*)(sw2p + (size_t)(q0 + swrow) * C_ + swc * 8);
            stw1 = *(const bf16x8*)(sw2p + (size_t)(q0 + 16 + swrow) * C_ + swc * 8);
            const int qf = q0 + fc16 * 8;
            if (qf < HW_) {
                const float* fb_ = filtn + (size_t)fct0 * HW_ + qf;
                sf00 = *(const f32x4*)(fb_);
                sf01 = *(const f32x4*)(fb_ + 4);
                sf10 = *(const f32x4*)(fb_ + (size_t)64 * HW_);
                sf11 = *(const f32x4*)(fb_ + (size_t)64 * HW_ + 4);
            } else {
                sf00 = sf01 = sf10 = sf11 = (f32x4){0.f, 0.f, 0.f, 0.f};
            }
        }

        // -- compute current chunk from LDS --
        B8 bq[2];
        #pragma unroll
        for (int h = 0; h < 2; ++h) {
            const u16* wr = &s_w[cur][16 * h + p][8 * g];
            const bf16x8 aw0 = *(const bf16x8*)(wr);
            const bf16x8 aw1 = *(const bf16x8*)(wr + 32);
            const bf16x8 aw2 = *(const bf16x8*)(wr + 64);
            const bf16x8 aw3 = *(const bf16x8*)(wr + 96);
            const f32x4 bi = *(const f32x4*)(sb2p + 32 * kt + 8 * g + 4 * h);
            #pragma unroll
            for (int f = 0; f < 2; ++f) {
                f32x4 c4 = (f32x4){0.f, 0.f, 0.f, 0.f};
                c4 = MFMA(aw0, bsh[0][f].v, c4);
                c4 = MFMA(aw1, bsh[1][f].v, c4);
                c4 = MFMA(aw2, bsh[2][f].v, c4);
                c4 = MFMA(aw3, bsh[3][f].v, c4);
                const float e0 = __expf(fminf(c4[0] + bi[0], 60.f));
                const float e1 = __expf(fminf(c4[1] + bi[1], 60.f));
                const float e2 = __expf(fminf(c4[2] + bi[2], 60.f));
                const float e3 = __expf(fminf(c4[3] + bi[3], 60.f));
                if (f == 0) psum0 += (e0 + e1) + (e2 + e3);
                else        psum1 += (e0 + e1) + (e2 + e3);
                bq[f].w[2 * h + 0] = pk(e0, e1);
                bq[f].w[2 * h + 1] = pk(e2, e3);
            }
        }
        #pragma unroll
        for (int ct = 0; ct < 8; ++ct) {
            const bf16x8 af = *(const bf16x8*)&s_f[cur][16 * ct + p][8 * g];
            pv[ct][0] = MFMA(af, bq[0].v, pv[ct][0]);
            pv[ct][1] = MFMA(af, bq[1].v, pv[ct][1]);
        }

        // -- write staged data into the other buffer --
        if (kt < 24) {
            *(bf16x8*)&s_w[nxt][swrow][swc * 8]      = stw0;
            *(bf16x8*)&s_w[nxt][16 + swrow][swc * 8] = stw1;
            B8 pf;
            pf.w[0] = pk(sf00[0], sf00[1]); pf.w[1] = pk(sf00[2], sf00[3]);
            pf.w[2] = pk(sf01[0], sf01[1]); pf.w[3] = pk(sf01[2], sf01[3]);
            *(bf16x8*)&s_f[nxt][frp][fc16 * 8] = pf.v;
            pf.w[0] = pk(sf10[0], sf10[1]); pf.w[1] = pk(sf10[2], sf10[3]);
            pf.w[2] = pk(sf11[0], sf11[1]); pf.w[3] = pk(sf11[2], sf11[3]);
            *(bf16x8*)&s_f[nxt][64 + frp][fc16 * 8] = pf.v;
        }
        __syncthreads();
    }
    psum0 += __shfl_xor(psum0, 16); psum0 += __shfl_xor(psum0, 32);
    psum1 += __shfl_xor(psum1, 16); psum1 += __shfl_xor(psum1, 32);
    const float inv0 = 1.f / psum0, inv1 = 1.f / psum1;

    // ---- C-pre: gh via MFMA (from bxc; k>=15 weight rows zero) -----------
    B8 bgh[4][2];
    #pragma unroll
    for (int ct = 0; ct < 8; ++ct) {
        const bf16x8 a_g = *(const bf16x8*)(gw1p + (16 * ct + p) * 32 + 8 * g);
        const int cb = 32 * (ct >> 1) + 8 * g + 4 * (ct & 1);
        const f32x4 b2 = *(const f32x4*)(gb1 + cb);
        const f32x4 gg = *(const f32x4*)(glob_gh + n * C_ + cb);
        const int m = ct >> 1, o = (ct & 1) * 2;
        #pragma unroll
        for (int f = 0; f < 2; ++f) {
            f32x4 cg = (f32x4){0.f, 0.f, 0.f, 0.f};
            cg = MFMA(a_g, bxc[f].v, cg);
            const float g0 = fmaxf(cg[0] + b2[0] + gg[0], 0.f), g1 = fmaxf(cg[1] + b2[1] + gg[1], 0.f);
            const float g2 = fmaxf(cg[2] + b2[2] + gg[2], 0.f), g3 = fmaxf(cg[3] + b2[3] + gg[3], 0.f);
            bgh[m][f].w[o] = pk(g0, g1); bgh[m][f].w[o + 1] = pk(g2, g3);
        }
    }

    // ---- C: gattn = sigmoid(gw2.gh + gb2); sf = gattn * pv * inv ---------
    B8 bsf[4][2];
    #pragma unroll
    for (int ct = 0; ct < 8; ++ct) {
        const u16* ar = gw2p + (16 * ct + p) * C_ + 8 * g;
        const bf16x8 a0 = *(const bf16x8*)(ar),      a1 = *(const bf16x8*)(ar + 32);
        const bf16x8 a2 = *(const bf16x8*)(ar + 64), a3 = *(const bf16x8*)(ar + 96);
        const int cb = 32 * (ct >> 1) + 8 * g + 4 * (ct & 1);
        const f32x4 gb = *(const f32x4*)(gb2 + cb);
        const int m = ct >> 1, o = (ct & 1) * 2;
        #pragma unroll
        for (int f = 0; f < 2; ++f) {
            f32x4 acc = (f32x4){0.f, 0.f, 0.f, 0.f};
            acc = MFMA(a0, bgh[0][f].v, acc);
            acc = MFMA(a1, bgh[1][f].v, acc);
            acc = MFMA(a2, bgh[2][f].v, acc);
            acc = MFMA(a3, bgh[3][f].v, acc);
            const float iv = f ? inv1 : inv0;
            const float s0 = pv[ct][f][0] * iv / (1.f + __expf(-(acc[0] + gb[0])));
            const float s1 = pv[ct][f][1] * iv / (1.f + __expf(-(acc[1] + gb[1])));
            const float s2 = pv[ct][f][2] * iv / (1.f + __expf(-(acc[2] + gb[2])));
            const float s3 = pv[ct][f][3] * iv / (1.f + __expf(-(acc[3] + gb[3])));
            bsf[m][f].w[o] = pk(s0, s1); bsf[m][f].w[o + 1] = pk(s2, s3);
        }
    }

    // ---- D: h1 = relu(fw1b.sf + fw1s.[x,cx,cy] + glob + fb1) -------------
    B8 bh1[4][2];
    #pragma unroll
    for (int ct = 0; ct < 8; ++ct) {
        const u16* ar = fw1bp + (16 * ct + p) * C_ + 8 * g;
        const bf16x8 a0 = *(const bf16x8*)(ar),      a1 = *(const bf16x8*)(ar + 32);
        const bf16x8 a2 = *(const bf16x8*)(ar + 64), a3 = *(const bf16x8*)(ar + 96);
        const bf16x8 a_s = *(const bf16x8*)(fw1sp + (16 * ct + p) * 32 + 8 * g);
        const int cb = 32 * (ct >> 1) + 8 * g + 4 * (ct & 1);
        const f32x4 fbv = *(const f32x4*)(fb1 + cb);
        const f32x4 gf  = *(const f32x4*)(glob_f1 + n * C_ + cb);
        const int m = ct >> 1, o = (ct & 1) * 2;
        #pragma unroll
        for (int f = 0; f < 2; ++f) {
            f32x4 acc = (f32x4){0.f, 0.f, 0.f, 0.f};
            acc = MFMA(a0, bsf[0][f].v, acc);
            acc = MFMA(a1, bsf[1][f].v, acc);
            acc = MFMA(a2, bsf[2][f].v, acc);
            acc = MFMA(a3, bsf[3][f].v, acc);
            acc = MFMA(a_s, bxc[f].v, acc);      // x/coord side-term
            const float h0 = fmaxf(acc[0] + fbv[0] + gf[0], 0.f);
            const float h1v = fmaxf(acc[1] + fbv[1] + gf[1], 0.f);
            const float h2 = fmaxf(acc[2] + fbv[2] + gf[2], 0.f);
            const float h3 = fmaxf(acc[3] + fbv[3] + gf[3], 0.f);
            bh1[m][f].w[o] = pk(h0, h1v); bh1[m][f].w[o + 1] = pk(h2, h3);
        }
    }

    // ---- E+F fused: h2 = relu(fw2.h1 + fb2); d += h2 * fw3 ---------------
    float d0[2] = {0.f, 0.f}, d1[2] = {0.f, 0.f}, d2[2] = {0.f, 0.f};
    #pragma unroll
    for (int ct = 0; ct < 8; ++ct) {
        const u16* ar = fw2p + (16 * ct + p) * C_ + 8 * g;
        const bf16x8 a0 = *(const bf16x8*)(ar),      a1 = *(const bf16x8*)(ar + 32);
        const bf16x8 a2 = *(const bf16x8*)(ar + 64), a3 = *(const bf16x8*)(ar + 96);
        const int cb = 32 * (ct >> 1) + 8 * g + 4 * (ct & 1);
        const f32x4 o4 = *(const f32x4*)(fb2 + cb);
        f32x4 w3r[4];
        #pragma unroll
        for (int r = 0; r < 4; ++r)
            w3r[r] = *(const f32x4*)(fw3p + (16 * ct + 4 * g + r) * 4);
        #pragma unroll
        for (int f = 0; f < 2; ++f) {
            f32x4 acc = (f32x4){0.f, 0.f, 0.f, 0.f};
            acc = MFMA(a0, bh1[0][f].v, acc);
            acc = MFMA(a1, bh1[1][f].v, acc);
            acc = MFMA(a2, bh1[2][f].v, acc);
            acc = MFMA(a3, bh1[3][f].v, acc);
            #pragma unroll
            for (int r = 0; r < 4; ++r) {
                const float h = fmaxf(acc[r] + o4[r], 0.f);
                d0[f] += h * w3r[r][0];
                d1[f] += h * w3r[r][1];
                d2[f] += h * w3r[r][2];
            }
        }
    }
    #pragma unroll
    for (int f = 0; f < 2; ++f) {
        float a0 = d0[f], a1 = d1[f], a2 = d2[f];
        a0 += __shfl_xor(a0, 16); a0 += __shfl_xor(a0, 32);
        a1 += __shfl_xor(a1, 16); a1 += __shfl_xor(a1, 32);
        a2 += __shfl_xor(a2, 16); a2 += __shfl_xor(a2, 32);
        if (g == 0) {
            const int pt = p + 16 * f;
            const int gp = n * P_ + pw + pt;
            out[gp * 3 + 0] = a0 + fb3[0] + s_x[wid][pt][0];
            out[gp * 3 + 1] = a1 + fb3[1] + s_x[wid][pt][1];
            out[gp * 3 + 2] = a2 + fb3[2] + s_x[wid][pt][2];
        }
    }
}

// ---------------------------------------------------------------------------
// Per-batch normalize in place (f32), 1024 threads.
// ---------------------------------------------------------------------------
__global__ __launch_bounds__(1024) void k_norm(float* __restrict__ out)
{
    __shared__ float red[48];
    __shared__ float red2[16];
    const int n = blockIdx.x, tid = threadIdx.x;
    float* pb = out + (size_t)n * P_ * 3;

    float sx = 0.f, sy = 0.f, sz = 0.f;
    for (int i = tid; i < P_; i += 1024) {
        sx += pb[i * 3 + 0]; sy += pb[i * 3 + 1]; sz += pb[i * 3 + 2];
    }
    #pragma unroll
    for (int m = 32; m >= 1; m >>= 1) {
        sx += __shfl_xor(sx, m); sy += __shfl_xor(sy, m); sz += __shfl_xor(sz, m);
    }
    const int wv = tid >> 6, ln = tid & 63;
    if (ln == 0) { red[wv * 3 + 0] = sx; red[wv * 3 + 1] = sy; red[wv * 3 + 2] = sz; }
    __syncthreads();
    float meanx = 0.f, meany = 0.f, meanz = 0.f;
    #pragma unroll
    for (int w = 0; w < 16; ++w) {
        meanx += red[w * 3 + 0]; meany += red[w * 3 + 1]; meanz += red[w * 3 + 2];
    }
    meanx /= (float)P_; meany /= (float)P_; meanz /= (float)P_;

    float mm = 0.f;
    for (int i = tid; i < P_; i += 1024) {
        const float dx = pb[i * 3 + 0] - meanx;
        const float dy = pb[i * 3 + 1] - meany;
        const float dz = pb[i * 3 + 2] - meanz;
        mm = fmaxf(mm, dx * dx + dy * dy + dz * dz);
    }
    #pragma unroll
    for (int m = 32; m >= 1; m >>= 1) mm = fmaxf(mm, __shfl_xor(mm, m));
    if (ln == 0) red2[wv] = mm;
    __syncthreads();
    mm = 0.f;
    #pragma unroll
    for (int w = 0; w < 16; ++w) mm = fmaxf(mm, red2[w]);
    const float scale = 1.f / (sqrtf(mm) + 1e-8f);

    for (int i = tid; i < P_; i += 1024) {
        pb[i * 3 + 0] = (pb[i * 3 + 0] - meanx) * scale;
        pb[i * 3 + 1] = (pb[i * 3 + 1] - meany) * scale;
        pb[i * 3 + 2] = (pb[i * 3 + 2] - meanz) * scale;
    }
}

// ---------------------------------------------------------------------------
extern "C" void kernel_launch(void* const* d_in, const int* in_sizes, int n_in,
                              void* d_out, int out_size, void* d_ws, size_t ws_size,
                              hipStream_t stream) {
    const float* points    = (const float*)d_in[0];
    const float* transform = (const float*)d_in[1];
    const float* filters   = (const float*)d_in[2];
    const float* enc_glob  = (const float*)d_in[3];
    const float* sw1 = (const float*)d_in[4];
    const float* sb1 = (const float*)d_in[5];
    const float* sw2 = (const float*)d_in[6];
    const float* sb2 = (const float*)d_in[7];
    const float* gw1 = (const float*)d_in[8];
    const float* gb1 = (const float*)d_in[9];
    const float* gw2 = (const float*)d_in[10];
    const float* gb2 = (const float*)d_in[11];
    const float* fw1 = (const float*)d_in[12];
    const float* fb1 = (const float*)d_in[13];
    const float* fw2 = (const float*)d_in[14];
    const float* fb2 = (const float*)d_in[15];
    const float* fw3 = (const float*)d_in[16];
    const float* fb3 = (const float*)d_in[17];

    char* ws = (char*)d_ws;
    u16*   sw2p    = (u16*)(ws + OFF_SW2P);
    u16*   sw1p    = (u16*)(ws + OFF_SW1P);
    u16*   gw1p    = (u16*)(ws + OFF_GW1P);
    u16*   gw2p    = (u16*)(ws + OFF_GW2P);
    u16*   fw1bp   = (u16*)(ws + OFF_FW1BP);
    u16*   fw2p    = (u16*)(ws + OFF_FW2P);
    float* sb2p    = (float*)(ws + OFF_SB2P);
    float* glob_gh = (float*)(ws + OFF_GLOBGH);
    float* glob_f1 = (float*)(ws + OFF_GLOBF1);
    u16*   fw1sp   = (u16*)(ws + OFF_FW1SP);
    float* fw3p    = (float*)(ws + OFF_FW3P);
    float* out     = (float*)d_out;

    k_prep<<<(E9 + 255) / 256, 256, 0, stream>>>(
        sw1, sw2, sb2, gw1, gw2, fw1, fw2, fw3, enc_glob,
        sw2p, sw1p, gw1p, gw2p, fw1bp, fw2p, sb2p, fw1sp, fw3p,
        glob_gh, glob_f1);
    k_mfma<<<N_ * (P_ / 128), 256, 0, stream>>>(
        points, transform, filters, sb1, gb1, gb2, fb1, fb2, fb3,
        sw1p, gw1p, sw2p, sb2p, gw2p, fw1bp, fw2p, fw1sp, fw3p,
        glob_gh, glob_f1, out);
    k_norm<<<N_, 1024, 0, stream>>>(out);
}

// Round 11
// 171.330 us; speedup vs baseline: 20.3209x; 1.2346x over previous
//
#include <hip/hip_runtime.h>
#include <hip/hip_bf16.h>

#define N_   16
#define P_   4096
#define C_   128
#define HW_  784
#define G_   512

typedef unsigned short u16;
typedef unsigned int   u32;
typedef __attribute__((ext_vector_type(8))) short bf16x8;
typedef __attribute__((ext_vector_type(4))) float f32x4;

union B8 { bf16x8 v; u32 w[4]; };

#define MFMA(a,b,c) __builtin_amdgcn_mfma_f32_16x16x32_bf16((a),(b),(c),0,0,0)

__device__ __forceinline__ u16 f2b(float f) {
    __hip_bfloat16 h = __float2bfloat16(f);
    return *reinterpret_cast<u16*>(&h);
}
__device__ __forceinline__ u32 pk(float lo, float hi) {
    return (u32)f2b(lo) | ((u32)f2b(hi) << 16);
}

// ---------------------------------------------------------------------------
// ws layout (bytes). bf16 A-operand matrices stored with M-dim rows PERMUTED
// so MFMA D-layout (row=4g+reg) lands in B-fragment k-order (k=8g+j):
//   row position (16ct + r) holds true idx 32*(ct>>1) + 8*(r>>2) + 4*(ct&1) + (r&3)
// filtp: bf16, c-rows permuted, q padded 784->800 with zeros (restored in
// round 11 so the kt loop stages bf16 directly: fewer regs + no pk VALU).
// ---------------------------------------------------------------------------
#define OFF_SW2P    0         // 800x128 bf16 (q rows permuted, q>=784 zero)
#define OFF_SW1P    204800    // 128x32 bf16 (out-c permuted, k>=15 zero)
#define OFF_GW1P    212992    // 128x32 bf16
#define OFF_GW2P    221184    // 128x128 bf16 (out-c permuted)
#define OFF_FW1BP   253952    // 128x128 bf16 (out-c permuted, fw1 rows 529+)
#define OFF_FW2P    286720    // 128x128 bf16 (out-c permuted)
#define OFF_SB2P    319488    // 800 f32 (plain order, q>=784 = -1e30)
#define OFF_GLOBGH  322688    // 16x128 f32
#define OFF_GLOBF1  330880    // 16x128 f32
#define OFF_FW1SP   339072    // 128x32 bf16 (perm rows; k<15 fw1[k], 15->527, 16->528, else 0)
#define OFF_FW3P    347264    // 128x4 f32 (perm rows of fw3, 4th = 0)
#define OFF_FILTP   349312    // 16x128x800 bf16 (c rows permuted, q>=784 zero)

// prep segment ends (flat thread index)
#define E0 102400   // sw2p  800*128
#define E1 110592   // sw1p  128*32
#define E2 118784   // gw1p  128*32
#define E3 135168   // gw2p  128*128
#define E4 151552   // fw1bp 128*128
#define E5 167936   // fw2p  128*128
#define E6 168736   // sb2p  800
#define E7 185120   // glob  2*16*128*4 (4-way k-split)
#define E8 189216   // fw1sp 128*32
#define E9 189728   // fw3p  128*4
#define E10 1828128 // filtp 16*128*800

__device__ __forceinline__ int perm_c(int row) {   // row pos -> true index
    const int ct = row >> 4, r = row & 15;
    return 32 * (ct >> 1) + 8 * (r >> 2) + 4 * (ct & 1) + (r & 3);
}

// ---------------------------------------------------------------------------
__global__ __launch_bounds__(256) void k_prep(
    const float* __restrict__ sw1, const float* __restrict__ sw2,
    const float* __restrict__ sb2, const float* __restrict__ gw1,
    const float* __restrict__ gw2, const float* __restrict__ fw1,
    const float* __restrict__ fw2, const float* __restrict__ fw3,
    const float* __restrict__ filters, const float* __restrict__ enc_glob,
    u16* __restrict__ sw2p, u16* __restrict__ sw1p, u16* __restrict__ gw1p,
    u16* __restrict__ gw2p, u16* __restrict__ fw1bp, u16* __restrict__ fw2p,
    float* __restrict__ sb2p, u16* __restrict__ fw1sp, float* __restrict__ fw3p,
    u16* __restrict__ filtp,
    float* __restrict__ glob_gh, float* __restrict__ glob_f1)
{
    const int idx = blockIdx.x * 256 + threadIdx.x;
    if (idx < E0) {                       // sw2p: q-rows permuted per 32-block
        const int r_new = idx >> 7, c = idx & 127;
        const int kt = r_new >> 5, o = r_new & 31, h = (o >> 4) & 1, r = o & 15;
        const int q = kt * 32 + 8 * (r >> 2) + 4 * h + (r & 3);
        sw2p[idx] = (q < HW_) ? f2b(sw2[c * HW_ + q]) : (u16)0;
    } else if (idx < E1) {                // sw1p
        const int t = idx - E0;
        const int row = t >> 5, k = t & 31;
        const int c = perm_c(row);
        sw1p[t] = (k < 15) ? f2b(sw1[k * C_ + c]) : (u16)0;
    } else if (idx < E2) {                // gw1p
        const int t = idx - E1;
        const int row = t >> 5, k = t & 31;
        const int c = perm_c(row);
        gw1p[t] = (k < 15) ? f2b(gw1[k * C_ + c]) : (u16)0;
    } else if (idx < E3) {                // gw2p
        const int t = idx - E2;
        const int row = t >> 7, ci = t & 127;
        gw2p[t] = f2b(gw2[ci * C_ + perm_c(row)]);
    } else if (idx < E4) {                // fw1bp (fw1 rows 529..656)
        const int t = idx - E3;
        const int row = t >> 7, ci = t & 127;
        fw1bp[t] = f2b(fw1[(529 + ci) * C_ + perm_c(row)]);
    } else if (idx < E5) {                // fw2p
        const int t = idx - E4;
        const int row = t >> 7, ci = t & 127;
        fw2p[t] = f2b(fw2[ci * C_ + perm_c(row)]);
    } else if (idx < E6) {                // sb2p: plain order + -inf tail
        const int q = idx - E5;
        sb2p[q] = (q < HW_) ? sb2[q] : -1e30f;
    } else if (idx < E7) {                // glob: 4 threads per output, k-split
        const int t = idx - E6;           // 0..16383
        const int sub = t & 3, r = t >> 2;
        const int which = r >> 11, nn = (r >> 7) & 15, c = r & 127;
        const float* W = which ? fw1 : gw1;
        const float* gv = enc_glob + nn * G_ + sub * 128;
        const float* Wp = W + (15 + sub * 128) * C_ + c;
        float acc = 0.f;
        for (int k = 0; k < 128; ++k) acc += gv[k] * Wp[k * C_];
        acc += __shfl_xor(acc, 1);
        acc += __shfl_xor(acc, 2);
        if (sub == 0) (which ? glob_f1 : glob_gh)[nn * C_ + c] = acc;
    } else if (idx < E8) {                // fw1sp: x/coord side-weights
        const int t = idx - E7;
        const int row = t >> 5, k = t & 31;
        const int c = perm_c(row);
        float v = 0.f;
        if (k < 15)       v = fw1[k * C_ + c];
        else if (k == 15) v = fw1[527 * C_ + c];
        else if (k == 16) v = fw1[528 * C_ + c];
        fw1sp[t] = f2b(v);
    } else if (idx < E9) {                // fw3p: perm rows of fw3, padded
        const int t = idx - E8;
        const int row = t >> 2, j = t & 3;
        fw3p[t] = (j < 3) ? fw3[perm_c(row) * 3 + j] : 0.f;
    } else if (idx < E10) {               // filtp: bf16, perm c-rows, q padded
        const int t = idx - E9;
        const int nn = t / 102400;
        const int rr = t % 102400;
        const int row = rr / 800, q = rr % 800;
        const int c = perm_c(row);
        filtp[t] = (q < HW_) ? f2b(filters[((size_t)nn * C_ + c) * HW_ + q]) : (u16)0;
    }
}

// ---------------------------------------------------------------------------
// Main kernel: 128 points/block, 4 waves, 32 points/wave.
// kt loop: LDS double-buffered chunks of sw2p (32x128) and filtp (128x32),
// both bf16, cooperatively staged once per block. T14 split: global loads
// at top of body, ds_write + barrier at bottom.
// __launch_bounds__(256, 2): cap unified VGPR+AGPR at 256/wave -> 2 waves
// per SIMD (round-10 counters showed 1 wave/SIMD = all latency exposed).
// Live set ~210 regs fits; WRITE_SIZE is the spill tripwire.
// ---------------------------------------------------------------------------
__global__ __launch_bounds__(256, 2) void k_mfma(
    const float* __restrict__ points, const float* __restrict__ transform,
    const float* __restrict__ sb1, const float* __restrict__ gb1,
    const float* __restrict__ gb2, const float* __restrict__ fb1,
    const float* __restrict__ fb2, const float* __restrict__ fb3,
    const u16* __restrict__ sw1p, const u16* __restrict__ gw1p,
    const u16* __restrict__ sw2p, const float* __restrict__ sb2p,
    const u16* __restrict__ gw2p, const u16* __restrict__ fw1bp,
    const u16* __restrict__ fw2p, const u16* __restrict__ fw1sp,
    const float* __restrict__ fw3p, const u16* __restrict__ filtp,
    const float* __restrict__ glob_gh, const float* __restrict__ glob_f1,
    float* __restrict__ out)
{
    __shared__ __align__(16) float s_x[4][32][16];   // 8 KB
    __shared__ __align__(16) u16 s_w[2][32][136];    // 17408 B (pad: 2-way free)
    __shared__ __align__(16) u16 s_f[2][128][36];    // 18432 B (pad: conflict-free)

    const int tid = threadIdx.x, wid = tid >> 6, lane = tid & 63;
    const int p = lane & 15, g = lane >> 4;
    // XCD swizzle: 512 blocks, 64-chunk per XCD -> 2 distinct n per XCD L2.
    const int bid = blockIdx.x;
    const int nb  = (bid & 7) * 64 + (bid >> 3);
    const int n   = nb >> 5;
    const int pw  = ((nb & 31) << 7) + (wid << 5);

    const u16* filtn = filtp + (size_t)n * 102400;
    // staging slot coords (fixed per thread)
    const int swrow = tid >> 4, swc = tid & 15;   // sw2p rows swrow/+16, 16B col swc
    const int frp   = tid >> 2, fc16 = tid & 3;   // filt rows frp/+64, 16B col fc16

    // ---- A1: inputs to LDS (per-wave, 32 points) -------------------------
    for (int i = lane; i < 512; i += 64) {
        const int pt = i >> 4, k = i & 15;
        const int gp = n * P_ + pw + pt;
        float v = 0.f;
        if (k < 3)       v = points[gp * 3 + k];
        else if (k < 15) v = transform[gp * 12 + k - 3];
        s_x[wid][pt][k] = v;
    }

    // ---- stage chunk kt=0 into buffer 0 ----------------------------------
    {
        const bf16x8 w0 = *(const bf16x8*)(sw2p + (size_t)swrow * C_ + swc * 8);
        const bf16x8 w1 = *(const bf16x8*)(sw2p + (size_t)(16 + swrow) * C_ + swc * 8);
        const bf16x8 f0 = *(const bf16x8*)(filtn + (size_t)frp * 800 + fc16 * 8);
        const bf16x8 f1 = *(const bf16x8*)(filtn + (size_t)(64 + frp) * 800 + fc16 * 8);
        *(bf16x8*)&s_w[0][swrow][swc * 8]      = w0;
        *(bf16x8*)&s_w[0][16 + swrow][swc * 8] = w1;
        *(bf16x8*)&s_f[0][frp][fc16 * 8]       = f0;
        *(bf16x8*)&s_f[0][64 + frp][fc16 * 8]  = f1;
    }
    __syncthreads();

    // ---- bxc: [x(15), cx, cy, 0...] as B-fragment (k = 8g+j) -------------
    B8 bxc[2];
    #pragma unroll
    for (int f = 0; f < 2; ++f) {
        bxc[f].w[0] = bxc[f].w[1] = bxc[f].w[2] = bxc[f].w[3] = 0u;
        const float* xs = &s_x[wid][p + 16 * f][0];
        const int pp = pw + p + 16 * f;
        const float cx = -1.f + 2.f * (float)(pp >> 6) / 63.f;
        const float cy = -1.f + 2.f * (float)(pp & 63) / 63.f;
        if (g == 0) {
            bxc[f].w[0] = pk(xs[0], xs[1]);  bxc[f].w[1] = pk(xs[2], xs[3]);
            bxc[f].w[2] = pk(xs[4], xs[5]);  bxc[f].w[3] = pk(xs[6], xs[7]);
        } else if (g == 1) {
            bxc[f].w[0] = pk(xs[8], xs[9]);  bxc[f].w[1] = pk(xs[10], xs[11]);
            bxc[f].w[2] = pk(xs[12], xs[13]); bxc[f].w[3] = pk(xs[14], cx);
        } else if (g == 2) {
            bxc[f].w[0] = pk(cy, 0.f);
        }
    }

    // ---- A2: sh via MFMA -------------------------------------------------
    B8 bsh[4][2];
    #pragma unroll
    for (int ct = 0; ct < 8; ++ct) {
        const bf16x8 a_s = *(const bf16x8*)(sw1p + (16 * ct + p) * 32 + 8 * g);
        const int cb = 32 * (ct >> 1) + 8 * g + 4 * (ct & 1);
        const f32x4 b1 = *(const f32x4*)(sb1 + cb);
        const int m = ct >> 1, o = (ct & 1) * 2;
        #pragma unroll
        for (int f = 0; f < 2; ++f) {
            f32x4 cs = (f32x4){0.f, 0.f, 0.f, 0.f};
            cs = MFMA(a_s, bxc[f].v, cs);
            const float s0 = fmaxf(cs[0] + b1[0], 0.f), s1 = fmaxf(cs[1] + b1[1], 0.f);
            const float s2 = fmaxf(cs[2] + b1[2], 0.f), s3 = fmaxf(cs[3] + b1[3], 0.f);
            bsh[m][f].w[o] = pk(s0, s1); bsh[m][f].w[o + 1] = pk(s2, s3);
        }
    }

    // ---- B: kt loop, double-buffered LDS ---------------------------------
    f32x4 pv[8][2];
    #pragma unroll
    for (int ct = 0; ct < 8; ++ct)
        #pragma unroll
        for (int f = 0; f < 2; ++f) pv[ct][f] = (f32x4){0.f, 0.f, 0.f, 0.f};
    float psum0 = 0.f, psum1 = 0.f;

    for (int kt = 0; kt < 25; ++kt) {
        const int cur = kt & 1, nxt = cur ^ 1;
        // -- T14: issue next chunk's global loads first --
        bf16x8 stw0, stw1, stf0, stf1;
        if (kt < 24) {
            const int q0 = 32 * (kt + 1);
            stw0 = *(const bf16x8*)(sw2p + (size_t)(q0 + swrow) * C_ + swc * 8);
            stw1 = *(const bf16x8*)(sw2p + (size_t)(q0 + 16 + swrow) * C_ + swc * 8);
            stf0 = *(const bf16x8*)(filtn + (size_t)frp * 800 + q0 + fc16 * 8);
            stf1 = *(const bf16x8*)(filtn + (size_t)(64 + frp) * 800 + q0 + fc16 * 8);
        }

        // -- compute current chunk from LDS --
        B8 bq[2];
        #pragma unroll
        for (int h = 0; h < 2; ++h) {
            const u16* wr = &s_w[cur][16 * h + p][8 * g];
            const bf16x8 aw0 = *(const bf16x8*)(wr);
            const bf16x8 aw1 = *(const bf16x8*)(wr + 32);
            const bf16x8 aw2 = *(const bf16x8*)(wr + 64);
            const bf16x8 aw3 = *(const bf16x8*)(wr + 96);
            const f32x4 bi = *(const f32x4*)(sb2p + 32 * kt + 8 * g + 4 * h);
            #pragma unroll
            for (int f = 0; f < 2; ++f) {
                f32x4 c4 = (f32x4){0.f, 0.f, 0.f, 0.f};
                c4 = MFMA(aw0, bsh[0][f].v, c4);
                c4 = MFMA(aw1, bsh[1][f].v, c4);
                c4 = MFMA(aw2, bsh[2][f].v, c4);
                c4 = MFMA(aw3, bsh[3][f].v, c4);
                const float e0 = __expf(fminf(c4[0] + bi[0], 60.f));
                const float e1 = __expf(fminf(c4[1] + bi[1], 60.f));
                const float e2 = __expf(fminf(c4[2] + bi[2], 60.f));
                const float e3 = __expf(fminf(c4[3] + bi[3], 60.f));
                if (f == 0) psum0 += (e0 + e1) + (e2 + e3);
                else        psum1 += (e0 + e1) + (e2 + e3);
                bq[f].w[2 * h + 0] = pk(e0, e1);
                bq[f].w[2 * h + 1] = pk(e2, e3);
            }
        }
        #pragma unroll
        for (int ct = 0; ct < 8; ++ct) {
            const bf16x8 af = *(const bf16x8*)&s_f[cur][16 * ct + p][8 * g];
            pv[ct][0] = MFMA(af, bq[0].v, pv[ct][0]);
            pv[ct][1] = MFMA(af, bq[1].v, pv[ct][1]);
        }

        // -- write staged data into the other buffer --
        if (kt < 24) {
            *(bf16x8*)&s_w[nxt][swrow][swc * 8]      = stw0;
            *(bf16x8*)&s_w[nxt][16 + swrow][swc * 8] = stw1;
            *(bf16x8*)&s_f[nxt][frp][fc16 * 8]       = stf0;
            *(bf16x8*)&s_f[nxt][64 + frp][fc16 * 8]  = stf1;
        }
        __syncthreads();
    }
    psum0 += __shfl_xor(psum0, 16); psum0 += __shfl_xor(psum0, 32);
    psum1 += __shfl_xor(psum1, 16); psum1 += __shfl_xor(psum1, 32);
    const float inv0 = 1.f / psum0, inv1 = 1.f / psum1;

    // ---- C-pre: gh via MFMA (from bxc; k>=15 weight rows zero) -----------
    B8 bgh[4][2];
    #pragma unroll
    for (int ct = 0; ct < 8; ++ct) {
        const bf16x8 a_g = *(const bf16x8*)(gw1p + (16 * ct + p) * 32 + 8 * g);
        const int cb = 32 * (ct >> 1) + 8 * g + 4 * (ct & 1);
        const f32x4 b2 = *(const f32x4*)(gb1 + cb);
        const f32x4 gg = *(const f32x4*)(glob_gh + n * C_ + cb);
        const int m = ct >> 1, o = (ct & 1) * 2;
        #pragma unroll
        for (int f = 0; f < 2; ++f) {
            f32x4 cg = (f32x4){0.f, 0.f, 0.f, 0.f};
            cg = MFMA(a_g, bxc[f].v, cg);
            const float g0 = fmaxf(cg[0] + b2[0] + gg[0], 0.f), g1 = fmaxf(cg[1] + b2[1] + gg[1], 0.f);
            const float g2 = fmaxf(cg[2] + b2[2] + gg[2], 0.f), g3 = fmaxf(cg[3] + b2[3] + gg[3], 0.f);
            bgh[m][f].w[o] = pk(g0, g1); bgh[m][f].w[o + 1] = pk(g2, g3);
        }
    }

    // ---- C: gattn = sigmoid(gw2.gh + gb2); sf = gattn * pv * inv ---------
    B8 bsf[4][2];
    #pragma unroll
    for (int ct = 0; ct < 8; ++ct) {
        const u16* ar = gw2p + (16 * ct + p) * C_ + 8 * g;
        const bf16x8 a0 = *(const bf16x8*)(ar),      a1 = *(const bf16x8*)(ar + 32);
        const bf16x8 a2 = *(const bf16x8*)(ar + 64), a3 = *(const bf16x8*)(ar + 96);
        const int cb = 32 * (ct >> 1) + 8 * g + 4 * (ct & 1);
        const f32x4 gb = *(const f32x4*)(gb2 + cb);
        const int m = ct >> 1, o = (ct & 1) * 2;
        #pragma unroll
        for (int f = 0; f < 2; ++f) {
            f32x4 acc = (f32x4){0.f, 0.f, 0.f, 0.f};
            acc = MFMA(a0, bgh[0][f].v, acc);
            acc = MFMA(a1, bgh[1][f].v, acc);
            acc = MFMA(a2, bgh[2][f].v, acc);
            acc = MFMA(a3, bgh[3][f].v, acc);
            const float iv = f ? inv1 : inv0;
            const float s0 = pv[ct][f][0] * iv / (1.f + __expf(-(acc[0] + gb[0])));
            const float s1 = pv[ct][f][1] * iv / (1.f + __expf(-(acc[1] + gb[1])));
            const float s2 = pv[ct][f][2] * iv / (1.f + __expf(-(acc[2] + gb[2])));
            const float s3 = pv[ct][f][3] * iv / (1.f + __expf(-(acc[3] + gb[3])));
            bsf[m][f].w[o] = pk(s0, s1); bsf[m][f].w[o + 1] = pk(s2, s3);
        }
    }

    // ---- D: h1 = relu(fw1b.sf + fw1s.[x,cx,cy] + glob + fb1) -------------
    B8 bh1[4][2];
    #pragma unroll
    for (int ct = 0; ct < 8; ++ct) {
        const u16* ar = fw1bp + (16 * ct + p) * C_ + 8 * g;
        const bf16x8 a0 = *(const bf16x8*)(ar),      a1 = *(const bf16x8*)(ar + 32);
        const bf16x8 a2 = *(const bf16x8*)(ar + 64), a3 = *(const bf16x8*)(ar + 96);
        const bf16x8 a_s = *(const bf16x8*)(fw1sp + (16 * ct + p) * 32 + 8 * g);
        const int cb = 32 * (ct >> 1) + 8 * g + 4 * (ct & 1);
        const f32x4 fbv = *(const f32x4*)(fb1 + cb);
        const f32x4 gf  = *(const f32x4*)(glob_f1 + n * C_ + cb);
        const int m = ct >> 1, o = (ct & 1) * 2;
        #pragma unroll
        for (int f = 0; f < 2; ++f) {
            f32x4 acc = (f32x4){0.f, 0.f, 0.f, 0.f};
            acc = MFMA(a0, bsf[0][f].v, acc);
            acc = MFMA(a1, bsf[1][f].v, acc);
            acc = MFMA(a2, bsf[2][f].v, acc);
            acc = MFMA(a3, bsf[3][f].v, acc);
            acc = MFMA(a_s, bxc[f].v, acc);      // x/coord side-term
            const float h0 = fmaxf(acc[0] + fbv[0] + gf[0], 0.f);
            const float h1v = fmaxf(acc[1] + fbv[1] + gf[1], 0.f);
            const float h2 = fmaxf(acc[2] + fbv[2] + gf[2], 0.f);
            const float h3 = fmaxf(acc[3] + fbv[3] + gf[3], 0.f);
            bh1[m][f].w[o] = pk(h0, h1v); bh1[m][f].w[o + 1] = pk(h2, h3);
        }
    }

    // ---- E+F fused: h2 = relu(fw2.h1 + fb2); d += h2 * fw3 ---------------
    float d0[2] = {0.f, 0.f}, d1[2] = {0.f, 0.f}, d2[2] = {0.f, 0.f};
    #pragma unroll
    for (int ct = 0; ct < 8; ++ct) {
        const u16* ar = fw2p + (16 * ct + p) * C_ + 8 * g;
        const bf16x8 a0 = *(const bf16x8*)(ar),      a1 = *(const bf16x8*)(ar + 32);
        const bf16x8 a2 = *(const bf16x8*)(ar + 64), a3 = *(const bf16x8*)(ar + 96);
        const int cb = 32 * (ct >> 1) + 8 * g + 4 * (ct & 1);
        const f32x4 o4 = *(const f32x4*)(fb2 + cb);
        f32x4 w3r[4];
        #pragma unroll
        for (int r = 0; r < 4; ++r)
            w3r[r] = *(const f32x4*)(fw3p + (16 * ct + 4 * g + r) * 4);
        #pragma unroll
        for (int f = 0; f < 2; ++f) {
            f32x4 acc = (f32x4){0.f, 0.f, 0.f, 0.f};
            acc = MFMA(a0, bh1[0][f].v, acc);
            acc = MFMA(a1, bh1[1][f].v, acc);
            acc = MFMA(a2, bh1[2][f].v, acc);
            acc = MFMA(a3, bh1[3][f].v, acc);
            #pragma unroll
            for (int r = 0; r < 4; ++r) {
                const float h = fmaxf(acc[r] + o4[r], 0.f);
                d0[f] += h * w3r[r][0];
                d1[f] += h * w3r[r][1];
                d2[f] += h * w3r[r][2];
            }
        }
    }
    #pragma unroll
    for (int f = 0; f < 2; ++f) {
        float a0 = d0[f], a1 = d1[f], a2 = d2[f];
        a0 += __shfl_xor(a0, 16); a0 += __shfl_xor(a0, 32);
        a1 += __shfl_xor(a1, 16); a1 += __shfl_xor(a1, 32);
        a2 += __shfl_xor(a2, 16); a2 += __shfl_xor(a2, 32);
        if (g == 0) {
            const int pt = p + 16 * f;
            const int gp = n * P_ + pw + pt;
            out[gp * 3 + 0] = a0 + fb3[0] + s_x[wid][pt][0];
            out[gp * 3 + 1] = a1 + fb3[1] + s_x[wid][pt][1];
            out[gp * 3 + 2] = a2 + fb3[2] + s_x[wid][pt][2];
        }
    }
}

// ---------------------------------------------------------------------------
// Per-batch normalize in place (f32), 1024 threads.
// ---------------------------------------------------------------------------
__global__ __launch_bounds__(1024) void k_norm(float* __restrict__ out)
{
    __shared__ float red[48];
    __shared__ float red2[16];
    const int n = blockIdx.x, tid = threadIdx.x;
    float* pb = out + (size_t)n * P_ * 3;

    float sx = 0.f, sy = 0.f, sz = 0.f;
    for (int i = tid; i < P_; i += 1024) {
        sx += pb[i * 3 + 0]; sy += pb[i * 3 + 1]; sz += pb[i * 3 + 2];
    }
    #pragma unroll
    for (int m = 32; m >= 1; m >>= 1) {
        sx += __shfl_xor(sx, m); sy += __shfl_xor(sy, m); sz += __shfl_xor(sz, m);
    }
    const int wv = tid >> 6, ln = tid & 63;
    if (ln == 0) { red[wv * 3 + 0] = sx; red[wv * 3 + 1] = sy; red[wv * 3 + 2] = sz; }
    __syncthreads();
    float meanx = 0.f, meany = 0.f, meanz = 0.f;
    #pragma unroll
    for (int w = 0; w < 16; ++w) {
        meanx += red[w * 3 + 0]; meany += red[w * 3 + 1]; meanz += red[w * 3 + 2];
    }
    meanx /= (float)P_; meany /= (float)P_; meanz /= (float)P_;

    float mm = 0.f;
    for (int i = tid; i < P_; i += 1024) {
        const float dx = pb[i * 3 + 0] - meanx;
        const float dy = pb[i * 3 + 1] - meany;
        const float dz = pb[i * 3 + 2] - meanz;
        mm = fmaxf(mm, dx * dx + dy * dy + dz * dz);
    }
    #pragma unroll
    for (int m = 32; m >= 1; m >>= 1) mm = fmaxf(mm, __shfl_xor(mm, m));
    if (ln == 0) red2[wv] = mm;
    __syncthreads();
    mm = 0.f;
    #pragma unroll
    for (int w = 0; w < 16; ++w) mm = fmaxf(mm, red2[w]);
    const float scale = 1.f / (sqrtf(mm) + 1e-8f);

    for (int i = tid; i < P_; i += 1024) {
        pb[i * 3 + 0] = (pb[i * 3 + 0] - meanx) * scale;
        pb[i * 3 + 1] = (pb[i * 3 + 1] - meany) * scale;
        pb[i * 3 + 2] = (pb[i * 3 + 2] - meanz) * scale;
    }
}

// ---------------------------------------------------------------------------
extern "C" void kernel_launch(void* const* d_in, const int* in_sizes, int n_in,
                              void* d_out, int out_size, void* d_ws, size_t ws_size,
                              hipStream_t stream) {
    const float* points    = (const float*)d_in[0];
    const float* transform = (const float*)d_in[1];
    const float* filters   = (const float*)d_in[2];
    const float* enc_glob  = (const float*)d_in[3];
    const float* sw1 = (const float*)d_in[4];
    const float* sb1 = (const float*)d_in[5];
    const float* sw2 = (const float*)d_in[6];
    const float* sb2 = (const float*)d_in[7];
    const float* gw1 = (const float*)d_in[8];
    const float* gb1 = (const float*)d_in[9];
    const float* gw2 = (const float*)d_in[10];
    const float* gb2 = (const float*)d_in[11];
    const float* fw1 = (const float*)d_in[12];
    const float* fb1 = (const float*)d_in[13];
    const float* fw2 = (const float*)d_in[14];
    const float* fb2 = (const float*)d_in[15];
    const float* fw3 = (const float*)d_in[16];
    const float* fb3 = (const float*)d_in[17];

    char* ws = (char*)d_ws;
    u16*   sw2p    = (u16*)(ws + OFF_SW2P);
    u16*   sw1p    = (u16*)(ws + OFF_SW1P);
    u16*   gw1p    = (u16*)(ws + OFF_GW1P);
    u16*   gw2p    = (u16*)(ws + OFF_GW2P);
    u16*   fw1bp   = (u16*)(ws + OFF_FW1BP);
    u16*   fw2p    = (u16*)(ws + OFF_FW2P);
    float* sb2p    = (float*)(ws + OFF_SB2P);
    float* glob_gh = (float*)(ws + OFF_GLOBGH);
    float* glob_f1 = (float*)(ws + OFF_GLOBF1);
    u16*   fw1sp   = (u16*)(ws + OFF_FW1SP);
    float* fw3p    = (float*)(ws + OFF_FW3P);
    u16*   filtp   = (u16*)(ws + OFF_FILTP);
    float* out     = (float*)d_out;

    k_prep<<<(E10 + 255) / 256, 256, 0, stream>>>(
        sw1, sw2, sb2, gw1, gw2, fw1, fw2, fw3, filters, enc_glob,
        sw2p, sw1p, gw1p, gw2p, fw1bp, fw2p, sb2p, fw1sp, fw3p, filtp,
        glob_gh, glob_f1);
    k_mfma<<<N_ * (P_ / 128), 256, 0, stream>>>(
        points, transform, sb1, gb1, gb2, fb1, fb2, fb3,
        sw1p, gw1p, sw2p, sb2p, gw2p, fw1bp, fw2p, fw1sp, fw3p, filtp,
        glob_gh, glob_f1, out);
    k_norm<<<N_, 1024, 0, stream>>>(out);
}